// Round 5
// baseline (99.185 us; speedup 1.0000x reference)
//
#include <hip/hip_runtime.h>
#include <hip/hip_bf16.h>

typedef __attribute__((ext_vector_type(8))) short bf16x8;
typedef __attribute__((ext_vector_type(4))) float f32x4;

#define NROWS 8192
#define EMB   512
#define NCLS  98
#define NCPAD 128
#define ALPHA_F 10.0f
#define BETA_F  2.0f

__device__ __forceinline__ unsigned short f2bf(float x) {
    unsigned u = __builtin_bit_cast(unsigned, x);
    u += 0x7FFF + ((u >> 16) & 1);
    return (unsigned short)(u >> 16);
}

// ---------------- KbT[c][k] = bf16( K[k][c] / ||K[:,c]|| ), c in [0,128) padded ----------------
__global__ __launch_bounds__(64) void kprep_kernel(const float* __restrict__ K,
                                                   unsigned short* __restrict__ KbT) {
    int c = blockIdx.x;      // 0..127
    int t = threadIdx.x;     // 0..63
    if (c < NCLS) {
        float v[8]; float s = 0.f;
        #pragma unroll
        for (int q = 0; q < 8; ++q) {
            float x = K[(size_t)(t + q * 64) * NCLS + c];
            v[q] = x; s = fmaf(x, x, s);
        }
        #pragma unroll
        for (int d = 32; d > 0; d >>= 1) s += __shfl_xor(s, d);
        float inv = 1.0f / sqrtf(s);
        #pragma unroll
        for (int q = 0; q < 8; ++q)
            KbT[(size_t)c * EMB + t + q * 64] = f2bf(v[q] * inv);
    } else {
        #pragma unroll
        for (int q = 0; q < 8; ++q)
            KbT[(size_t)c * EMB + t + q * 64] = 0;
    }
}

// ---------------- class sums V[c][k], usum[k], hist — one pass over X ----------------
#define CS_DIMS 64
#define CS_ROWS 256
__global__ __launch_bounds__(256) void classsum_kernel(
        const float* __restrict__ X, const int* __restrict__ T,
        float* __restrict__ V, float* __restrict__ usum, int* __restrict__ hist) {
    __shared__ float Vloc[NCLS * CS_DIMS];   // 24.5 KB
    const int tid = threadIdx.x;
    for (int i = tid; i < NCLS * CS_DIMS; i += 256) Vloc[i] = 0.f;
    __syncthreads();

    const int d0 = blockIdx.x * CS_DIMS;     // 8 dim-chunks
    const int r0 = blockIdx.y * CS_ROWS;     // 32 row-chunks
    const int lane = tid & 63, w = tid >> 6;

    if (blockIdx.x == 0) atomicAdd(&hist[T[r0 + tid]], 1);   // hist once per row

    for (int r = w; r < CS_ROWS; r += 4) {
        int row = r0 + r;
        int cls = T[row];
        float x = X[(size_t)row * EMB + d0 + lane];
        atomicAdd(&Vloc[cls * CS_DIMS + lane], x);   // wave-uniform cls, per-lane dim: conflict-free
    }
    __syncthreads();
    for (int i = tid; i < NCLS * CS_DIMS; i += 256) {
        int c = i >> 6, d = i & 63;
        atomicAdd(&V[(size_t)c * EMB + d0 + d], Vloc[i]);
    }
    if (tid < CS_DIMS) {
        float s = 0.f;
        #pragma unroll 2
        for (int c = 0; c < NCLS; ++c) s += Vloc[c * CS_DIMS + tid];
        atomicAdd(&usum[d0 + tid], s);
    }
}

// ---------------- fused main: MFMA logits + softmax/argmax/loss + row pos/neg ----------------
// one wave per 16 rows; lane (c0,g) streams row row0+c0, dim block g*8 per K-step
__global__ __launch_bounds__(64) void main_kernel(
        const float* __restrict__ X, const unsigned short* __restrict__ KbT,
        const int* __restrict__ T, const int* __restrict__ hist,
        const float* __restrict__ V, const float* __restrict__ usum,
        double* __restrict__ acc, double* __restrict__ posneg) {
    const int row0 = blockIdx.x * 16;
    const int lane = threadIdx.x;
    const int c0 = lane & 15, g = lane >> 4;
    const int myrow = row0 + c0;
    const int tmy = T[myrow];
    const float* vrow = V + (size_t)tmy * EMB;

    f32x4 av[8] = {};
    float s = 0.f, sm = 0.f; double d = 0.0;

    for (int kk = 0; kk < EMB; kk += 32) {
        const float* xp = &X[(size_t)myrow * EMB + kk + g * 8];
        float4 x0 = *(const float4*)xp, x1 = *(const float4*)(xp + 4);
        const float* up = &usum[kk + g * 8];
        float4 u0 = *(const float4*)up, u1 = *(const float4*)(up + 4);
        const float* vp = &vrow[kk + g * 8];
        float4 v0 = *(const float4*)vp, v1 = *(const float4*)(vp + 4);

        float xf[8] = {x0.x, x0.y, x0.z, x0.w, x1.x, x1.y, x1.z, x1.w};
        float uf[8] = {u0.x, u0.y, u0.z, u0.w, u1.x, u1.y, u1.z, u1.w};
        float vf[8] = {v0.x, v0.y, v0.z, v0.w, v1.x, v1.y, v1.z, v1.w};

        bf16x8 a;
        #pragma unroll
        for (int j = 0; j < 8; ++j) {
            s  = fmaf(xf[j], uf[j], s);
            sm = fmaf(xf[j], vf[j], sm);
            d  = fma((double)xf[j], (double)xf[j], d);
            a[j] = (short)f2bf(xf[j]);
        }
        #pragma unroll
        for (int f = 0; f < 8; ++f) {
            bf16x8 b = *(const bf16x8*)&KbT[(size_t)(f * 16 + c0) * EMB + kk + g * 8];
            av[f] = __builtin_amdgcn_mfma_f32_16x16x32_bf16(a, b, av[f], 0, 0, 0);
        }
    }

    // ---- per-row s/sm/d: reduce over the 4 g-groups (lanes with same c0) ----
    s  += __shfl_xor(s, 16);  s  += __shfl_xor(s, 32);
    sm += __shfl_xor(sm, 16); sm += __shfl_xor(sm, 32);
    d  += __shfl_xor(d, 16);  d  += __shfl_xor(d, 32);

    double pc = 0.0, nc = 0.0;
    if (g == 0) {
        int h = hist[tmy];
        float pos_sum; int pos_cnt;
        if (d < 1.0) { pos_sum = sm;            pos_cnt = h;     }
        else         { pos_sum = sm - (float)d; pos_cnt = h - 1; }
        float neg_sum = s - sm;
        pc = (double)(pos_sum / (float)pos_cnt);
        nc = (double)(neg_sum / (float)(NROWS - h));
    }
    #pragma unroll
    for (int m = 1; m < 16; m <<= 1) { pc += __shfl_xor(pc, m); nc += __shfl_xor(nc, m); }
    if (lane == 0) {
        int b = (blockIdx.x & 63) * 2;
        atomicAdd(&posneg[b],     pc);
        atomicAdd(&posneg[b + 1], nc);
    }

    // ---- logits epilogue: softmax / argmax / loss ----
    float lossacc = 0.f, pracc = 0.f;
    #pragma unroll
    for (int r = 0; r < 4; ++r) {
        const int row = row0 + g * 4 + r;
        const int tgt = T[row];
        float vals[8];
        float m = -1e30f;
        #pragma unroll
        for (int f = 0; f < 8; ++f) {
            int col = f * 16 + c0;
            float cosv = fminf(1.f, fmaxf(-1.f, av[f][r]));
            float logit = (cosv - (col == tgt ? BETA_F : 0.f)) * ALPHA_F;
            if (col >= NCLS) logit = -1e30f;
            vals[f] = logit;
            m = fmaxf(m, logit);
        }
        #pragma unroll
        for (int dd = 1; dd < 16; dd <<= 1) m = fmaxf(m, __shfl_xor(m, dd));

        float se = 0.f, tval = -1e30f;
        float bv = -1e30f; int bi = 0x7fffffff;
        #pragma unroll
        for (int f = 0; f < 8; ++f) {
            int col = f * 16 + c0;
            se += __expf(vals[f] - m) * (col < NCLS ? 1.f : 0.f);
            if (col == tgt) tval = vals[f];
            if (vals[f] > bv) { bv = vals[f]; bi = col; }
        }
        #pragma unroll
        for (int dd = 1; dd < 16; dd <<= 1) {
            se += __shfl_xor(se, dd);
            tval = fmaxf(tval, __shfl_xor(tval, dd));
            float ov = __shfl_xor(bv, dd); int oi = __shfl_xor(bi, dd);
            if (ov > bv || (ov == bv && oi < bi)) { bv = ov; bi = oi; }
        }
        if (c0 == 0) {
            lossacc += (m + logf(se)) - tval;
            pracc += (bi == tgt) ? 1.f : 0.f;
        }
    }
    lossacc += __shfl_xor(lossacc, 16); lossacc += __shfl_xor(lossacc, 32);
    pracc   += __shfl_xor(pracc, 16);   pracc   += __shfl_xor(pracc, 32);
    if (lane == 0) {
        atomicAdd(&acc[0], (double)lossacc);
        atomicAdd(&acc[1], (double)pracc);
    }
}

__global__ void out2_kernel(const double* __restrict__ acc,
                            const double* __restrict__ posneg,
                            float* __restrict__ out) {
    if (threadIdx.x == 0) {
        double p = 0.0, n = 0.0;
        for (int i = 0; i < 64; ++i) { p += posneg[i * 2]; n += posneg[i * 2 + 1]; }
        out[0] = (float)(acc[0] / NROWS);
        out[1] = (float)(acc[1] / NROWS);
        out[2] = (float)(p / NROWS);
        out[3] = (float)(n / NROWS);
    }
}

// ================= fallback f32 path (tiny workspace) =================
#define BM 64
#define BN 64
#define BK 32
#define LDA 68

__global__ void hist_kernel(const int* __restrict__ t, int* __restrict__ hist) {
    int i = blockIdx.x * blockDim.x + threadIdx.x;
    if (i < NROWS) atomicAdd(&hist[t[i]], 1);
}

__global__ void colnorm_kernel(const float* __restrict__ K, float* __restrict__ colinv) {
    int c = blockIdx.x;
    float s = 0.f;
    for (int k = threadIdx.x; k < EMB; k += 64) {
        float v = K[k * NCLS + c];
        s = fmaf(v, v, s);
    }
    #pragma unroll
    for (int off = 32; off > 0; off >>= 1) s += __shfl_down(s, off);
    if (threadIdx.x == 0) colinv[c] = 1.0f / sqrtf(s);
}

__global__ __launch_bounds__(256) void simred_kernel(
        const float* __restrict__ X, const int* __restrict__ T,
        float* __restrict__ S, float* __restrict__ SAME) {
    __shared__ float As[BK * LDA];
    __shared__ float Bs[BK * LDA];
    __shared__ int   trow[BM], tcol[BN];
    __shared__ float redS[BM], redSame[BM];

    const int tid = threadIdx.x;
    const int tx = tid & 15, ty = tid >> 4;
    const int i0 = blockIdx.x * BM, j0 = blockIdx.y * BN;

    if (tid < BM) {
        trow[tid] = T[i0 + tid];
        tcol[tid] = T[j0 + tid];
        redS[tid] = 0.f;
        redSame[tid] = 0.f;
    }

    float c[4][4] = {};
    for (int kk = 0; kk < EMB; kk += BK) {
        #pragma unroll
        for (int q = 0; q < 2; ++q) {
            int l  = tid * 2 + q;
            int r  = l >> 3;
            int kq = (l & 7) << 2;
            const float4 va = *(const float4*)(X + (size_t)(i0 + r) * EMB + kk + kq);
            As[(kq + 0) * LDA + r] = va.x;
            As[(kq + 1) * LDA + r] = va.y;
            As[(kq + 2) * LDA + r] = va.z;
            As[(kq + 3) * LDA + r] = va.w;
            const float4 vb = *(const float4*)(X + (size_t)(j0 + r) * EMB + kk + kq);
            Bs[(kq + 0) * LDA + r] = vb.x;
            Bs[(kq + 1) * LDA + r] = vb.y;
            Bs[(kq + 2) * LDA + r] = vb.z;
            Bs[(kq + 3) * LDA + r] = vb.w;
        }
        __syncthreads();
        #pragma unroll
        for (int k = 0; k < BK; ++k) {
            float4 a4 = *(const float4*)&As[k * LDA + ty * 4];
            float4 b4 = *(const float4*)&Bs[k * LDA + tx * 4];
            float a[4] = {a4.x, a4.y, a4.z, a4.w};
            float b[4] = {b4.x, b4.y, b4.z, b4.w};
            #pragma unroll
            for (int i = 0; i < 4; ++i)
                #pragma unroll
                for (int j = 0; j < 4; ++j)
                    c[i][j] = fmaf(a[i], b[j], c[i][j]);
        }
        __syncthreads();
    }

    #pragma unroll
    for (int i = 0; i < 4; ++i) {
        int r = ty * 4 + i;
        int tr = trow[r];
        float s = 0.f, sm = 0.f;
        #pragma unroll
        for (int j = 0; j < 4; ++j) {
            float v = c[i][j];
            s += v;
            if (tcol[tx * 4 + j] == tr) sm += v;
        }
        atomicAdd(&redS[r], s);
        atomicAdd(&redSame[r], sm);
    }
    __syncthreads();
    if (tid < BM) {
        atomicAdd(&S[i0 + tid],    redS[tid]);
        atomicAdd(&SAME[i0 + tid], redSame[tid]);
    }
}

__global__ __launch_bounds__(128) void loss_kernel(
        const float* __restrict__ X, const int* __restrict__ T,
        const float* __restrict__ K, const float* __restrict__ colinv,
        double* __restrict__ acc) {
    const int row = blockIdx.x;
    const int tid = threadIdx.x;
    __shared__ float xs[EMB];
    *(float4*)&xs[tid * 4] = *(const float4*)&X[(size_t)row * EMB + tid * 4];
    __syncthreads();

    const int tgt = T[row];
    const int c = tid;
    float logit = -1e30f;
    if (c < NCLS) {
        float d = 0.f;
        #pragma unroll 4
        for (int k = 0; k < EMB; ++k) d = fmaf(K[k * NCLS + c], xs[k], d);
        float cosv = d * colinv[c];
        cosv = fminf(1.f, fmaxf(-1.f, cosv));
        logit = (cosv - (c == tgt ? BETA_F : 0.f)) * ALPHA_F;
    }

    __shared__ float rv[128];
    __shared__ int   ri[128];
    __shared__ float Lt;
    if (c == tgt) Lt = logit;

    rv[tid] = logit;
    __syncthreads();
    #pragma unroll
    for (int s = 64; s > 0; s >>= 1) {
        if (tid < s) rv[tid] = fmaxf(rv[tid], rv[tid + s]);
        __syncthreads();
    }
    const float m = rv[0];
    __syncthreads();

    rv[tid] = (c < NCLS) ? expf(logit - m) : 0.f;
    __syncthreads();
    #pragma unroll
    for (int s = 64; s > 0; s >>= 1) {
        if (tid < s) rv[tid] += rv[tid + s];
        __syncthreads();
    }
    const float lse = m + logf(rv[0]);
    __syncthreads();

    rv[tid] = logit;
    ri[tid] = (c < NCLS) ? c : 0x7fffffff;
    __syncthreads();
    #pragma unroll
    for (int s = 64; s > 0; s >>= 1) {
        if (tid < s) {
            float vo = rv[tid + s]; int io = ri[tid + s];
            if (vo > rv[tid] || (vo == rv[tid] && io < ri[tid])) { rv[tid] = vo; ri[tid] = io; }
        }
        __syncthreads();
    }

    if (tid == 0) {
        float loss_i = lse - Lt;
        atomicAdd(&acc[0], (double)loss_i);
        atomicAdd(&acc[1], (ri[0] == tgt) ? 1.0 : 0.0);
    }
}

__global__ void finalize_kernel(
        const float* __restrict__ X, const int* __restrict__ T,
        const int* __restrict__ hist, const float* __restrict__ S,
        const float* __restrict__ SAME, double* __restrict__ acc) {
    int r = blockIdx.x * blockDim.x + threadIdx.x;
    if (r >= NROWS) return;
    const float* x = X + (size_t)r * EMB;
    double d = 0.0;
    for (int k = 0; k < EMB; ++k) d = fma((double)x[k], (double)x[k], d);
    int h = hist[T[r]];
    float same = SAME[r];
    float pos_sum; int pos_cnt;
    if (d < 1.0) { pos_sum = same;            pos_cnt = h;     }
    else         { pos_sum = same - (float)d; pos_cnt = h - 1; }
    float neg_sum = S[r] - same;
    int   neg_cnt = NROWS - h;
    atomicAdd(&acc[2], (double)(pos_sum / (float)pos_cnt));
    atomicAdd(&acc[3], (double)(neg_sum / (float)neg_cnt));
}

__global__ void out_kernel(const double* __restrict__ acc, float* __restrict__ out) {
    if (threadIdx.x == 0) {
        out[0] = (float)(acc[0] / NROWS);
        out[1] = (float)(acc[1] / NROWS);
        out[2] = (float)(acc[2] / NROWS);
        out[3] = (float)(acc[3] / NROWS);
    }
}

extern "C" void kernel_launch(void* const* d_in, const int* in_sizes, int n_in,
                              void* d_out, int out_size, void* d_ws, size_t ws_size,
                              hipStream_t stream) {
    const float* X = (const float*)d_in[0];   // [8192, 512]
    const int*   T = (const int*)d_in[1];     // [8192]
    const float* K = (const float*)d_in[2];   // [512, 98]
    float* out = (float*)d_out;               // 4 scalars

    const size_t KBT_BYTES = (size_t)NCPAD * EMB * sizeof(unsigned short);  // 128 KB
    // misc block: acc(4 dbl) + posneg(128 dbl) + hist(100 int) + V(98*512 f) + usum(512 f)
    const size_t MISC_BYTES = 4 * 8 + 128 * 8 + 100 * 4
                            + (size_t)(NCLS * EMB + EMB) * 4;

    if (ws_size >= KBT_BYTES + MISC_BYTES + 256) {
        // fast path: class-sum factorization + fused MFMA logits/row-stats
        unsigned short* KbT = (unsigned short*)d_ws;
        char* misc = (char*)d_ws + KBT_BYTES;
        double* acc    = (double*)misc;
        double* posneg = acc + 4;
        int*    hist   = (int*)(posneg + 128);
        float*  V      = (float*)(hist + 100);
        float*  usum   = V + (size_t)NCLS * EMB;

        hipMemsetAsync(misc, 0, MISC_BYTES, stream);
        kprep_kernel<<<NCPAD, 64, 0, stream>>>(K, KbT);
        classsum_kernel<<<dim3(EMB / CS_DIMS, NROWS / CS_ROWS), 256, 0, stream>>>(X, T, V, usum, hist);
        main_kernel<<<NROWS / 16, 64, 0, stream>>>(X, KbT, T, hist, V, usum, acc, posneg);
        out2_kernel<<<1, 64, 0, stream>>>(acc, posneg, out);
    } else {
        // fallback: f32 path (small workspace)
        const size_t FB_BYTES = sizeof(double) * 4 + sizeof(int) * NCLS
                              + sizeof(float) * (NCLS + 2 * NROWS);
        double* acc    = (double*)d_ws;
        int*    hist   = (int*)(acc + 4);
        float*  colinv = (float*)(hist + NCLS);
        float*  S      = colinv + NCLS;
        float*  SAME   = S + NROWS;

        hipMemsetAsync(d_ws, 0, FB_BYTES, stream);
        hist_kernel<<<(NROWS + 255) / 256, 256, 0, stream>>>(T, hist);
        colnorm_kernel<<<NCLS, 64, 0, stream>>>(K, colinv);
        simred_kernel<<<dim3(NROWS / BM, NROWS / BN), 256, 0, stream>>>(X, T, S, SAME);
        loss_kernel<<<NROWS, 128, 0, stream>>>(X, T, K, colinv, acc);
        finalize_kernel<<<(NROWS + 255) / 256, 256, 0, stream>>>(X, T, hist, S, SAME, acc);
        out_kernel<<<1, 64, 0, stream>>>(acc, out);
    }
}

// Round 6
// 92.663 us; speedup vs baseline: 1.0704x; 1.0704x over previous
//
#include <hip/hip_runtime.h>
#include <hip/hip_bf16.h>

typedef __attribute__((ext_vector_type(8))) short bf16x8;
typedef __attribute__((ext_vector_type(4))) float f32x4;

#define NROWS 8192
#define EMB   512
#define NCLS  98
#define NCPAD 128
#define ALPHA_F 10.0f
#define BETA_F  2.0f

__device__ __forceinline__ unsigned short f2bf(float x) {
    unsigned u = __builtin_bit_cast(unsigned, x);
    u += 0x7FFF + ((u >> 16) & 1);
    return (unsigned short)(u >> 16);
}

// ---------------- class sums V[c][k], usum[k], hist + kprep (fused) ----------------
// grid (9, 32): bx<8 -> classsum dim-chunk, bx==8 -> kprep (class = by*4 + wave)
#define CS_DIMS 64
#define CS_ROWS 256
__global__ __launch_bounds__(256) void classsum_kernel(
        const float* __restrict__ X, const int* __restrict__ T,
        const float* __restrict__ K,
        float* __restrict__ V, float* __restrict__ usum, int* __restrict__ hist,
        unsigned short* __restrict__ KbT) {
    __shared__ float Vloc[NCLS * CS_DIMS];   // 24.5 KB
    const int tid = threadIdx.x;
    const int lane = tid & 63, w = tid >> 6;

    if (blockIdx.x == 8) {
        // ---- kprep: KbT[c][k] = bf16(K[k][c]/||K[:,c]||), one class per wave ----
        int c = blockIdx.y * 4 + w;            // 0..127
        if (c < NCLS) {
            float v[8]; float s = 0.f;
            #pragma unroll
            for (int q = 0; q < 8; ++q) {
                float x = K[(size_t)(lane + q * 64) * NCLS + c];
                v[q] = x; s = fmaf(x, x, s);
            }
            #pragma unroll
            for (int d = 32; d > 0; d >>= 1) s += __shfl_xor(s, d);
            float inv = 1.0f / sqrtf(s);
            #pragma unroll
            for (int q = 0; q < 8; ++q)
                KbT[(size_t)c * EMB + lane + q * 64] = f2bf(v[q] * inv);
        } else {
            #pragma unroll
            for (int q = 0; q < 8; ++q)
                KbT[(size_t)c * EMB + lane + q * 64] = 0;
        }
        return;
    }

    for (int i = tid; i < NCLS * CS_DIMS; i += 256) Vloc[i] = 0.f;
    __syncthreads();

    const int d0 = blockIdx.x * CS_DIMS;     // 8 dim-chunks
    const int r0 = blockIdx.y * CS_ROWS;     // 32 row-chunks

    if (blockIdx.x == 0) atomicAdd(&hist[T[r0 + tid]], 1);   // hist once per row

    for (int r = w; r < CS_ROWS; r += 4) {
        int row = r0 + r;
        int cls = T[row];
        float x = X[(size_t)row * EMB + d0 + lane];
        atomicAdd(&Vloc[cls * CS_DIMS + lane], x);   // wave-uniform cls, lane-owned bank
    }
    __syncthreads();
    for (int i = tid; i < NCLS * CS_DIMS; i += 256) {
        int c = i >> 6, d = i & 63;
        atomicAdd(&V[(size_t)c * EMB + d0 + d], Vloc[i]);
    }
    if (tid < CS_DIMS) {
        float s = 0.f;
        #pragma unroll 2
        for (int c = 0; c < NCLS; ++c) s += Vloc[c * CS_DIMS + tid];
        atomicAdd(&usum[d0 + tid], s);
    }
}

// ---------------- fused main: 4 waves per 16 rows, K-split by wave ----------------
// wave w owns dims [w*128, w*128+128); lane (c0,g): row row0+c0, dim sub-block g*8
__global__ __launch_bounds__(256) void main_kernel(
        const float* __restrict__ X, const unsigned short* __restrict__ KbT,
        const int* __restrict__ T, const int* __restrict__ hist,
        const float* __restrict__ V, const float* __restrict__ usum,
        double* __restrict__ acc, double* __restrict__ posneg) {
    __shared__ f32x4  redAV[3][8][64];        // 24 KB
    __shared__ float  redS[4][16], redSM[4][16];
    __shared__ double redD[4][16];

    const int row0 = blockIdx.x * 16;
    const int tid = threadIdx.x;
    const int w = tid >> 6, lane = tid & 63;
    const int c0 = lane & 15, g = lane >> 4;
    const int myrow = row0 + c0;
    const int tmy = T[myrow];
    const float* vrow = V + (size_t)tmy * EMB;

    f32x4 av[8] = {};
    float s = 0.f, sm = 0.f; double d = 0.0;

    #pragma unroll
    for (int t = 0; t < 4; ++t) {
        const int kk = w * 128 + t * 32;
        const float* xp = &X[(size_t)myrow * EMB + kk + g * 8];
        float4 x0 = *(const float4*)xp, x1 = *(const float4*)(xp + 4);
        const float* up = &usum[kk + g * 8];
        float4 u0 = *(const float4*)up, u1 = *(const float4*)(up + 4);
        const float* vp = &vrow[kk + g * 8];
        float4 v0 = *(const float4*)vp, v1 = *(const float4*)(vp + 4);

        float xf[8] = {x0.x, x0.y, x0.z, x0.w, x1.x, x1.y, x1.z, x1.w};
        float uf[8] = {u0.x, u0.y, u0.z, u0.w, u1.x, u1.y, u1.z, u1.w};
        float vf[8] = {v0.x, v0.y, v0.z, v0.w, v1.x, v1.y, v1.z, v1.w};

        bf16x8 a;
        #pragma unroll
        for (int j = 0; j < 8; ++j) {
            s  = fmaf(xf[j], uf[j], s);
            sm = fmaf(xf[j], vf[j], sm);
            d  = fma((double)xf[j], (double)xf[j], d);
            a[j] = (short)f2bf(xf[j]);
        }
        #pragma unroll
        for (int f = 0; f < 8; ++f) {
            bf16x8 b = *(const bf16x8*)&KbT[(size_t)(f * 16 + c0) * EMB + kk + g * 8];
            av[f] = __builtin_amdgcn_mfma_f32_16x16x32_bf16(a, b, av[f], 0, 0, 0);
        }
    }

    // intra-wave reduce of s/sm/d over the 4 g-groups
    s  += __shfl_xor(s, 16);  s  += __shfl_xor(s, 32);
    sm += __shfl_xor(sm, 16); sm += __shfl_xor(sm, 32);
    d  += __shfl_xor(d, 16);  d  += __shfl_xor(d, 32);

    // cross-wave reduce via LDS
    if (w > 0) {
        #pragma unroll
        for (int f = 0; f < 8; ++f) redAV[w - 1][f][lane] = av[f];
    }
    if (g == 0) { redS[w][c0] = s; redSM[w][c0] = sm; redD[w][c0] = d; }
    __syncthreads();
    if (w != 0) return;

    #pragma unroll
    for (int f = 0; f < 8; ++f) {
        av[f] += redAV[0][f][lane];
        av[f] += redAV[1][f][lane];
        av[f] += redAV[2][f][lane];
    }
    if (g == 0) {
        #pragma unroll
        for (int ww = 1; ww < 4; ++ww) {
            s += redS[ww][c0]; sm += redSM[ww][c0]; d += redD[ww][c0];
        }
    }

    // ---- per-row pos/neg contributions (g==0 lanes own rows) ----
    double pc = 0.0, nc = 0.0;
    if (g == 0) {
        int h = hist[tmy];
        float pos_sum; int pos_cnt;
        if (d < 1.0) { pos_sum = sm;            pos_cnt = h;     }
        else         { pos_sum = sm - (float)d; pos_cnt = h - 1; }
        float neg_sum = s - sm;
        pc = (double)(pos_sum / (float)pos_cnt);
        nc = (double)(neg_sum / (float)(NROWS - h));
    }
    #pragma unroll
    for (int m = 1; m < 16; m <<= 1) { pc += __shfl_xor(pc, m); nc += __shfl_xor(nc, m); }
    if (lane == 0) {
        int b = (blockIdx.x & 63) * 2;
        atomicAdd(&posneg[b],     pc);
        atomicAdd(&posneg[b + 1], nc);
    }

    // ---- logits epilogue: softmax / argmax / loss ----
    float lossacc = 0.f, pracc = 0.f;
    #pragma unroll
    for (int r = 0; r < 4; ++r) {
        const int row = row0 + g * 4 + r;
        const int tgt = T[row];
        float vals[8];
        float m = -1e30f;
        #pragma unroll
        for (int f = 0; f < 8; ++f) {
            int col = f * 16 + c0;
            float cosv = fminf(1.f, fmaxf(-1.f, av[f][r]));
            float logit = (cosv - (col == tgt ? BETA_F : 0.f)) * ALPHA_F;
            if (col >= NCLS) logit = -1e30f;
            vals[f] = logit;
            m = fmaxf(m, logit);
        }
        #pragma unroll
        for (int dd = 1; dd < 16; dd <<= 1) m = fmaxf(m, __shfl_xor(m, dd));

        float se = 0.f, tval = -1e30f;
        float bv = -1e30f; int bi = 0x7fffffff;
        #pragma unroll
        for (int f = 0; f < 8; ++f) {
            int col = f * 16 + c0;
            se += __expf(vals[f] - m) * (col < NCLS ? 1.f : 0.f);
            if (col == tgt) tval = vals[f];
            if (vals[f] > bv) { bv = vals[f]; bi = col; }
        }
        #pragma unroll
        for (int dd = 1; dd < 16; dd <<= 1) {
            se += __shfl_xor(se, dd);
            tval = fmaxf(tval, __shfl_xor(tval, dd));
            float ov = __shfl_xor(bv, dd); int oi = __shfl_xor(bi, dd);
            if (ov > bv || (ov == bv && oi < bi)) { bv = ov; bi = oi; }
        }
        if (c0 == 0) {
            lossacc += (m + logf(se)) - tval;
            pracc += (bi == tgt) ? 1.f : 0.f;
        }
    }
    lossacc += __shfl_xor(lossacc, 16); lossacc += __shfl_xor(lossacc, 32);
    pracc   += __shfl_xor(pracc, 16);   pracc   += __shfl_xor(pracc, 32);
    if (lane == 0) {
        atomicAdd(&acc[0], (double)lossacc);
        atomicAdd(&acc[1], (double)pracc);
    }
}

__global__ void out2_kernel(const double* __restrict__ acc,
                            const double* __restrict__ posneg,
                            float* __restrict__ out) {
    if (threadIdx.x == 0) {
        double p = 0.0, n = 0.0;
        for (int i = 0; i < 64; ++i) { p += posneg[i * 2]; n += posneg[i * 2 + 1]; }
        out[0] = (float)(acc[0] / NROWS);
        out[1] = (float)(acc[1] / NROWS);
        out[2] = (float)(p / NROWS);
        out[3] = (float)(n / NROWS);
    }
}

// ================= fallback f32 path (tiny workspace) =================
#define BM 64
#define BN 64
#define BK 32
#define LDA 68

__global__ void hist_kernel(const int* __restrict__ t, int* __restrict__ hist) {
    int i = blockIdx.x * blockDim.x + threadIdx.x;
    if (i < NROWS) atomicAdd(&hist[t[i]], 1);
}

__global__ void colnorm_kernel(const float* __restrict__ K, float* __restrict__ colinv) {
    int c = blockIdx.x;
    float s = 0.f;
    for (int k = threadIdx.x; k < EMB; k += 64) {
        float v = K[k * NCLS + c];
        s = fmaf(v, v, s);
    }
    #pragma unroll
    for (int off = 32; off > 0; off >>= 1) s += __shfl_down(s, off);
    if (threadIdx.x == 0) colinv[c] = 1.0f / sqrtf(s);
}

__global__ __launch_bounds__(256) void simred_kernel(
        const float* __restrict__ X, const int* __restrict__ T,
        float* __restrict__ S, float* __restrict__ SAME) {
    __shared__ float As[BK * LDA];
    __shared__ float Bs[BK * LDA];
    __shared__ int   trow[BM], tcol[BN];
    __shared__ float redS[BM], redSame[BM];

    const int tid = threadIdx.x;
    const int tx = tid & 15, ty = tid >> 4;
    const int i0 = blockIdx.x * BM, j0 = blockIdx.y * BN;

    if (tid < BM) {
        trow[tid] = T[i0 + tid];
        tcol[tid] = T[j0 + tid];
        redS[tid] = 0.f;
        redSame[tid] = 0.f;
    }

    float c[4][4] = {};
    for (int kk = 0; kk < EMB; kk += BK) {
        #pragma unroll
        for (int q = 0; q < 2; ++q) {
            int l  = tid * 2 + q;
            int r  = l >> 3;
            int kq = (l & 7) << 2;
            const float4 va = *(const float4*)(X + (size_t)(i0 + r) * EMB + kk + kq);
            As[(kq + 0) * LDA + r] = va.x;
            As[(kq + 1) * LDA + r] = va.y;
            As[(kq + 2) * LDA + r] = va.z;
            As[(kq + 3) * LDA + r] = va.w;
            const float4 vb = *(const float4*)(X + (size_t)(j0 + r) * EMB + kk + kq);
            Bs[(kq + 0) * LDA + r] = vb.x;
            Bs[(kq + 1) * LDA + r] = vb.y;
            Bs[(kq + 2) * LDA + r] = vb.z;
            Bs[(kq + 3) * LDA + r] = vb.w;
        }
        __syncthreads();
        #pragma unroll
        for (int k = 0; k < BK; ++k) {
            float4 a4 = *(const float4*)&As[k * LDA + ty * 4];
            float4 b4 = *(const float4*)&Bs[k * LDA + tx * 4];
            float a[4] = {a4.x, a4.y, a4.z, a4.w};
            float b[4] = {b4.x, b4.y, b4.z, b4.w};
            #pragma unroll
            for (int i = 0; i < 4; ++i)
                #pragma unroll
                for (int j = 0; j < 4; ++j)
                    c[i][j] = fmaf(a[i], b[j], c[i][j]);
        }
        __syncthreads();
    }

    #pragma unroll
    for (int i = 0; i < 4; ++i) {
        int r = ty * 4 + i;
        int tr = trow[r];
        float s = 0.f, sm = 0.f;
        #pragma unroll
        for (int j = 0; j < 4; ++j) {
            float v = c[i][j];
            s += v;
            if (tcol[tx * 4 + j] == tr) sm += v;
        }
        atomicAdd(&redS[r], s);
        atomicAdd(&redSame[r], sm);
    }
    __syncthreads();
    if (tid < BM) {
        atomicAdd(&S[i0 + tid],    redS[tid]);
        atomicAdd(&SAME[i0 + tid], redSame[tid]);
    }
}

__global__ __launch_bounds__(128) void loss_kernel(
        const float* __restrict__ X, const int* __restrict__ T,
        const float* __restrict__ K, const float* __restrict__ colinv,
        double* __restrict__ acc) {
    const int row = blockIdx.x;
    const int tid = threadIdx.x;
    __shared__ float xs[EMB];
    *(float4*)&xs[tid * 4] = *(const float4*)&X[(size_t)row * EMB + tid * 4];
    __syncthreads();

    const int tgt = T[row];
    const int c = tid;
    float logit = -1e30f;
    if (c < NCLS) {
        float d = 0.f;
        #pragma unroll 4
        for (int k = 0; k < EMB; ++k) d = fmaf(K[k * NCLS + c], xs[k], d);
        float cosv = d * colinv[c];
        cosv = fminf(1.f, fmaxf(-1.f, cosv));
        logit = (cosv - (c == tgt ? BETA_F : 0.f)) * ALPHA_F;
    }

    __shared__ float rv[128];
    __shared__ int   ri[128];
    __shared__ float Lt;
    if (c == tgt) Lt = logit;

    rv[tid] = logit;
    __syncthreads();
    #pragma unroll
    for (int s = 64; s > 0; s >>= 1) {
        if (tid < s) rv[tid] = fmaxf(rv[tid], rv[tid + s]);
        __syncthreads();
    }
    const float m = rv[0];
    __syncthreads();

    rv[tid] = (c < NCLS) ? expf(logit - m) : 0.f;
    __syncthreads();
    #pragma unroll
    for (int s = 64; s > 0; s >>= 1) {
        if (tid < s) rv[tid] += rv[tid + s];
        __syncthreads();
    }
    const float lse = m + logf(rv[0]);
    __syncthreads();

    rv[tid] = logit;
    ri[tid] = (c < NCLS) ? c : 0x7fffffff;
    __syncthreads();
    #pragma unroll
    for (int s = 64; s > 0; s >>= 1) {
        if (tid < s) {
            float vo = rv[tid + s]; int io = ri[tid + s];
            if (vo > rv[tid] || (vo == rv[tid] && io < ri[tid])) { rv[tid] = vo; ri[tid] = io; }
        }
        __syncthreads();
    }

    if (tid == 0) {
        float loss_i = lse - Lt;
        atomicAdd(&acc[0], (double)loss_i);
        atomicAdd(&acc[1], (ri[0] == tgt) ? 1.0 : 0.0);
    }
}

__global__ void finalize_kernel(
        const float* __restrict__ X, const int* __restrict__ T,
        const int* __restrict__ hist, const float* __restrict__ S,
        const float* __restrict__ SAME, double* __restrict__ acc) {
    int r = blockIdx.x * blockDim.x + threadIdx.x;
    if (r >= NROWS) return;
    const float* x = X + (size_t)r * EMB;
    double d = 0.0;
    for (int k = 0; k < EMB; ++k) d = fma((double)x[k], (double)x[k], d);
    int h = hist[T[r]];
    float same = SAME[r];
    float pos_sum; int pos_cnt;
    if (d < 1.0) { pos_sum = same;            pos_cnt = h;     }
    else         { pos_sum = same - (float)d; pos_cnt = h - 1; }
    float neg_sum = S[r] - same;
    int   neg_cnt = NROWS - h;
    atomicAdd(&acc[2], (double)(pos_sum / (float)pos_cnt));
    atomicAdd(&acc[3], (double)(neg_sum / (float)neg_cnt));
}

__global__ void out_kernel(const double* __restrict__ acc, float* __restrict__ out) {
    if (threadIdx.x == 0) {
        out[0] = (float)(acc[0] / NROWS);
        out[1] = (float)(acc[1] / NROWS);
        out[2] = (float)(acc[2] / NROWS);
        out[3] = (float)(acc[3] / NROWS);
    }
}

extern "C" void kernel_launch(void* const* d_in, const int* in_sizes, int n_in,
                              void* d_out, int out_size, void* d_ws, size_t ws_size,
                              hipStream_t stream) {
    const float* X = (const float*)d_in[0];   // [8192, 512]
    const int*   T = (const int*)d_in[1];     // [8192]
    const float* K = (const float*)d_in[2];   // [512, 98]
    float* out = (float*)d_out;               // 4 scalars

    const size_t KBT_BYTES = (size_t)NCPAD * EMB * sizeof(unsigned short);  // 128 KB
    // misc block: acc(4 dbl) + posneg(128 dbl) + hist(100 int) + V(98*512 f) + usum(512 f)
    const size_t MISC_BYTES = 4 * 8 + 128 * 8 + 100 * 4
                            + (size_t)(NCLS * EMB + EMB) * 4;

    if (ws_size >= KBT_BYTES + MISC_BYTES + 256) {
        // fast path: class-sum factorization + fused MFMA logits/row-stats
        unsigned short* KbT = (unsigned short*)d_ws;
        char* misc = (char*)d_ws + KBT_BYTES;
        double* acc    = (double*)misc;
        double* posneg = acc + 4;
        int*    hist   = (int*)(posneg + 128);
        float*  V      = (float*)(hist + 100);
        float*  usum   = V + (size_t)NCLS * EMB;

        hipMemsetAsync(misc, 0, MISC_BYTES, stream);
        classsum_kernel<<<dim3(9, NROWS / CS_ROWS), 256, 0, stream>>>(X, T, K, V, usum, hist, KbT);
        main_kernel<<<NROWS / 16, 256, 0, stream>>>(X, KbT, T, hist, V, usum, acc, posneg);
        out2_kernel<<<1, 64, 0, stream>>>(acc, posneg, out);
    } else {
        // fallback: f32 path (small workspace)
        const size_t FB_BYTES = sizeof(double) * 4 + sizeof(int) * NCLS
                              + sizeof(float) * (NCLS + 2 * NROWS);
        double* acc    = (double*)d_ws;
        int*    hist   = (int*)(acc + 4);
        float*  colinv = (float*)(hist + NCLS);
        float*  S      = colinv + NCLS;
        float*  SAME   = S + NROWS;

        hipMemsetAsync(d_ws, 0, FB_BYTES, stream);
        hist_kernel<<<(NROWS + 255) / 256, 256, 0, stream>>>(T, hist);
        colnorm_kernel<<<NCLS, 64, 0, stream>>>(K, colinv);
        simred_kernel<<<dim3(NROWS / BM, NROWS / BN), 256, 0, stream>>>(X, T, S, SAME);
        loss_kernel<<<NROWS, 128, 0, stream>>>(X, T, K, colinv, acc);
        finalize_kernel<<<(NROWS + 255) / 256, 256, 0, stream>>>(X, T, hist, S, SAME, acc);
        out_kernel<<<1, 64, 0, stream>>>(acc, out);
    }
}

// Round 7
// 79.941 us; speedup vs baseline: 1.2407x; 1.1592x over previous
//
#include <hip/hip_runtime.h>
#include <hip/hip_bf16.h>

typedef __attribute__((ext_vector_type(8))) short bf16x8;
typedef __attribute__((ext_vector_type(4))) float f32x4;

#define NROWS 8192
#define EMB   512
#define NCLS  98
#define NCPAD 128
#define ALPHA_F 10.0f
#define BETA_F  2.0f

__device__ __forceinline__ unsigned short f2bf(float x) {
    unsigned u = __builtin_bit_cast(unsigned, x);
    u += 0x7FFF + ((u >> 16) & 1);
    return (unsigned short)(u >> 16);
}

// ---------------- class sums V[c][k], usum[k], hist + kprep (fused) ----------------
// grid (9, 128): bx<8 -> classsum dim-chunk, bx==8 & by<32 -> kprep
#define CS_DIMS 64
#define CS_ROWS 64
__global__ __launch_bounds__(256) void classsum_kernel(
        const float* __restrict__ X, const int* __restrict__ T,
        const float* __restrict__ K,
        float* __restrict__ V, float* __restrict__ usum, int* __restrict__ hist,
        unsigned short* __restrict__ KbT) {
    __shared__ float Vloc[NCLS * CS_DIMS];   // 24.5 KB
    const int tid = threadIdx.x;
    const int lane = tid & 63, w = tid >> 6;

    if (blockIdx.x == 8) {
        // ---- kprep: KbT[c][k] = bf16(K[k][c]/||K[:,c]||), one class per wave ----
        if (blockIdx.y >= 32) return;
        int c = blockIdx.y * 4 + w;            // 0..127
        if (c < NCLS) {
            float v[8]; float s = 0.f;
            #pragma unroll
            for (int q = 0; q < 8; ++q) {
                float x = K[(size_t)(lane + q * 64) * NCLS + c];
                v[q] = x; s = fmaf(x, x, s);
            }
            #pragma unroll
            for (int d = 32; d > 0; d >>= 1) s += __shfl_xor(s, d);
            float inv = 1.0f / sqrtf(s);
            #pragma unroll
            for (int q = 0; q < 8; ++q)
                KbT[(size_t)c * EMB + lane + q * 64] = f2bf(v[q] * inv);
        } else {
            #pragma unroll
            for (int q = 0; q < 8; ++q)
                KbT[(size_t)c * EMB + lane + q * 64] = 0;
        }
        return;
    }

    for (int i = tid; i < NCLS * CS_DIMS; i += 256) Vloc[i] = 0.f;
    __syncthreads();

    const int d0 = blockIdx.x * CS_DIMS;     // 8 dim-chunks
    const int r0 = blockIdx.y * CS_ROWS;     // 128 row-chunks

    if (blockIdx.x == 0 && tid < CS_ROWS)
        atomicAdd(&hist[T[r0 + tid]], 1);    // hist once per row

    #pragma unroll 4
    for (int r = w; r < CS_ROWS; r += 4) {
        int row = r0 + r;
        int cls = T[row];                    // wave-uniform -> scalar load
        float x = X[(size_t)row * EMB + d0 + lane];
        atomicAdd(&Vloc[cls * CS_DIMS + lane], x);   // lane-owned bank, conflict-free
    }
    __syncthreads();
    for (int i = tid; i < NCLS * CS_DIMS; i += 256) {
        float v = Vloc[i];
        if (v != 0.f) {                      // ~47 of 98 classes touched per 64 rows
            int c = i >> 6, d = i & 63;
            atomicAdd(&V[(size_t)c * EMB + d0 + d], v);
        }
    }
    if (tid < CS_DIMS) {
        float s = 0.f;
        #pragma unroll 2
        for (int c = 0; c < NCLS; ++c) s += Vloc[c * CS_DIMS + tid];
        atomicAdd(&usum[d0 + tid], s);
    }
}

// ---------------- fused main: 8 waves per 16 rows, K-split by wave ----------------
// wave w owns dims [w*64, w*64+64); lane (c0,g): row row0+c0, dim sub-block g*8
__global__ __launch_bounds__(512) void main_kernel(
        const float* __restrict__ X, const unsigned short* __restrict__ KbT,
        const int* __restrict__ T, const int* __restrict__ hist,
        const float* __restrict__ V, const float* __restrict__ usum,
        double* __restrict__ acc, double* __restrict__ posneg) {
    __shared__ f32x4  redAV[4][8][64];        // 32 KB, two-stage reuse
    __shared__ float  redS[8][16], redSM[8][16];
    __shared__ double redD[8][16];

    const int row0 = blockIdx.x * 16;
    const int tid = threadIdx.x;
    const int w = tid >> 6, lane = tid & 63;
    const int c0 = lane & 15, g = lane >> 4;
    const int myrow = row0 + c0;
    const int tmy = T[myrow];
    const float* vrow = V + (size_t)tmy * EMB;

    f32x4 av[8] = {};
    float s = 0.f, sm = 0.f; double d = 0.0;

    #pragma unroll
    for (int t = 0; t < 2; ++t) {
        const int kk = w * 64 + t * 32;
        const float* xp = &X[(size_t)myrow * EMB + kk + g * 8];
        float4 x0 = *(const float4*)xp, x1 = *(const float4*)(xp + 4);
        const float* up = &usum[kk + g * 8];
        float4 u0 = *(const float4*)up, u1 = *(const float4*)(up + 4);
        const float* vp = &vrow[kk + g * 8];
        float4 v0 = *(const float4*)vp, v1 = *(const float4*)(vp + 4);

        float xf[8] = {x0.x, x0.y, x0.z, x0.w, x1.x, x1.y, x1.z, x1.w};
        float uf[8] = {u0.x, u0.y, u0.z, u0.w, u1.x, u1.y, u1.z, u1.w};
        float vf[8] = {v0.x, v0.y, v0.z, v0.w, v1.x, v1.y, v1.z, v1.w};

        bf16x8 a;
        #pragma unroll
        for (int j = 0; j < 8; ++j) {
            s  = fmaf(xf[j], uf[j], s);
            sm = fmaf(xf[j], vf[j], sm);
            d  = fma((double)xf[j], (double)xf[j], d);
            a[j] = (short)f2bf(xf[j]);
        }
        #pragma unroll
        for (int f = 0; f < 8; ++f) {
            bf16x8 b = *(const bf16x8*)&KbT[(size_t)(f * 16 + c0) * EMB + kk + g * 8];
            av[f] = __builtin_amdgcn_mfma_f32_16x16x32_bf16(a, b, av[f], 0, 0, 0);
        }
    }

    // intra-wave reduce of s/sm/d over the 4 g-groups
    s  += __shfl_xor(s, 16);  s  += __shfl_xor(s, 32);
    sm += __shfl_xor(sm, 16); sm += __shfl_xor(sm, 32);
    d  += __shfl_xor(d, 16);  d  += __shfl_xor(d, 32);
    if (g == 0) { redS[w][c0] = s; redSM[w][c0] = sm; redD[w][c0] = d; }

    // cross-wave reduce of av: 8 -> 4 -> 1 via LDS (two stages, slots reused)
    if (w >= 4) {
        #pragma unroll
        for (int f = 0; f < 8; ++f) redAV[w - 4][f][lane] = av[f];
    }
    __syncthreads();
    if (w < 4) {
        #pragma unroll
        for (int f = 0; f < 8; ++f) av[f] += redAV[w][f][lane];
    }
    __syncthreads();
    if (w >= 1 && w < 4) {
        #pragma unroll
        for (int f = 0; f < 8; ++f) redAV[w - 1][f][lane] = av[f];
    }
    __syncthreads();
    if (w != 0) return;

    #pragma unroll
    for (int f = 0; f < 8; ++f) {
        av[f] += redAV[0][f][lane];
        av[f] += redAV[1][f][lane];
        av[f] += redAV[2][f][lane];
    }
    if (g == 0) {
        #pragma unroll
        for (int ww = 1; ww < 8; ++ww) {
            s += redS[ww][c0]; sm += redSM[ww][c0]; d += redD[ww][c0];
        }
    }

    // ---- per-row pos/neg contributions (g==0 lanes own rows) ----
    double pc = 0.0, nc = 0.0;
    if (g == 0) {
        int h = hist[tmy];
        float pos_sum; int pos_cnt;
        if (d < 1.0) { pos_sum = sm;            pos_cnt = h;     }
        else         { pos_sum = sm - (float)d; pos_cnt = h - 1; }
        float neg_sum = s - sm;
        pc = (double)(pos_sum / (float)pos_cnt);
        nc = (double)(neg_sum / (float)(NROWS - h));
    }
    #pragma unroll
    for (int m = 1; m < 16; m <<= 1) { pc += __shfl_xor(pc, m); nc += __shfl_xor(nc, m); }
    if (lane == 0) {
        int b = (blockIdx.x & 63) * 2;
        atomicAdd(&posneg[b],     pc);
        atomicAdd(&posneg[b + 1], nc);
    }

    // ---- logits epilogue: softmax / argmax / loss ----
    float lossacc = 0.f, pracc = 0.f;
    #pragma unroll
    for (int r = 0; r < 4; ++r) {
        const int row = row0 + g * 4 + r;
        const int tgt = T[row];
        float vals[8];
        float m = -1e30f;
        #pragma unroll
        for (int f = 0; f < 8; ++f) {
            int col = f * 16 + c0;
            float cosv = fminf(1.f, fmaxf(-1.f, av[f][r]));
            float logit = (cosv - (col == tgt ? BETA_F : 0.f)) * ALPHA_F;
            if (col >= NCLS) logit = -1e30f;
            vals[f] = logit;
            m = fmaxf(m, logit);
        }
        #pragma unroll
        for (int dd = 1; dd < 16; dd <<= 1) m = fmaxf(m, __shfl_xor(m, dd));

        float se = 0.f, tval = -1e30f;
        float bv = -1e30f; int bi = 0x7fffffff;
        #pragma unroll
        for (int f = 0; f < 8; ++f) {
            int col = f * 16 + c0;
            se += __expf(vals[f] - m) * (col < NCLS ? 1.f : 0.f);
            if (col == tgt) tval = vals[f];
            if (vals[f] > bv) { bv = vals[f]; bi = col; }
        }
        #pragma unroll
        for (int dd = 1; dd < 16; dd <<= 1) {
            se += __shfl_xor(se, dd);
            tval = fmaxf(tval, __shfl_xor(tval, dd));
            float ov = __shfl_xor(bv, dd); int oi = __shfl_xor(bi, dd);
            if (ov > bv || (ov == bv && oi < bi)) { bv = ov; bi = oi; }
        }
        if (c0 == 0) {
            lossacc += (m + logf(se)) - tval;
            pracc += (bi == tgt) ? 1.f : 0.f;
        }
    }
    lossacc += __shfl_xor(lossacc, 16); lossacc += __shfl_xor(lossacc, 32);
    pracc   += __shfl_xor(pracc, 16);   pracc   += __shfl_xor(pracc, 32);
    if (lane == 0) {
        atomicAdd(&acc[0], (double)lossacc);
        atomicAdd(&acc[1], (double)pracc);
    }
}

__global__ void out2_kernel(const double* __restrict__ acc,
                            const double* __restrict__ posneg,
                            float* __restrict__ out) {
    if (threadIdx.x == 0) {
        double p = 0.0, n = 0.0;
        for (int i = 0; i < 64; ++i) { p += posneg[i * 2]; n += posneg[i * 2 + 1]; }
        out[0] = (float)(acc[0] / NROWS);
        out[1] = (float)(acc[1] / NROWS);
        out[2] = (float)(p / NROWS);
        out[3] = (float)(n / NROWS);
    }
}

// ================= fallback f32 path (tiny workspace) =================
#define BM 64
#define BN 64
#define BK 32
#define LDA 68

__global__ void hist_kernel(const int* __restrict__ t, int* __restrict__ hist) {
    int i = blockIdx.x * blockDim.x + threadIdx.x;
    if (i < NROWS) atomicAdd(&hist[t[i]], 1);
}

__global__ void colnorm_kernel(const float* __restrict__ K, float* __restrict__ colinv) {
    int c = blockIdx.x;
    float s = 0.f;
    for (int k = threadIdx.x; k < EMB; k += 64) {
        float v = K[k * NCLS + c];
        s = fmaf(v, v, s);
    }
    #pragma unroll
    for (int off = 32; off > 0; off >>= 1) s += __shfl_down(s, off);
    if (threadIdx.x == 0) colinv[c] = 1.0f / sqrtf(s);
}

__global__ __launch_bounds__(256) void simred_kernel(
        const float* __restrict__ X, const int* __restrict__ T,
        float* __restrict__ S, float* __restrict__ SAME) {
    __shared__ float As[BK * LDA];
    __shared__ float Bs[BK * LDA];
    __shared__ int   trow[BM], tcol[BN];
    __shared__ float redS[BM], redSame[BM];

    const int tid = threadIdx.x;
    const int tx = tid & 15, ty = tid >> 4;
    const int i0 = blockIdx.x * BM, j0 = blockIdx.y * BN;

    if (tid < BM) {
        trow[tid] = T[i0 + tid];
        tcol[tid] = T[j0 + tid];
        redS[tid] = 0.f;
        redSame[tid] = 0.f;
    }

    float c[4][4] = {};
    for (int kk = 0; kk < EMB; kk += BK) {
        #pragma unroll
        for (int q = 0; q < 2; ++q) {
            int l  = tid * 2 + q;
            int r  = l >> 3;
            int kq = (l & 7) << 2;
            const float4 va = *(const float4*)(X + (size_t)(i0 + r) * EMB + kk + kq);
            As[(kq + 0) * LDA + r] = va.x;
            As[(kq + 1) * LDA + r] = va.y;
            As[(kq + 2) * LDA + r] = va.z;
            As[(kq + 3) * LDA + r] = va.w;
            const float4 vb = *(const float4*)(X + (size_t)(j0 + r) * EMB + kk + kq);
            Bs[(kq + 0) * LDA + r] = vb.x;
            Bs[(kq + 1) * LDA + r] = vb.y;
            Bs[(kq + 2) * LDA + r] = vb.z;
            Bs[(kq + 3) * LDA + r] = vb.w;
        }
        __syncthreads();
        #pragma unroll
        for (int k = 0; k < BK; ++k) {
            float4 a4 = *(const float4*)&As[k * LDA + ty * 4];
            float4 b4 = *(const float4*)&Bs[k * LDA + tx * 4];
            float a[4] = {a4.x, a4.y, a4.z, a4.w};
            float b[4] = {b4.x, b4.y, b4.z, b4.w};
            #pragma unroll
            for (int i = 0; i < 4; ++i)
                #pragma unroll
                for (int j = 0; j < 4; ++j)
                    c[i][j] = fmaf(a[i], b[j], c[i][j]);
        }
        __syncthreads();
    }

    #pragma unroll
    for (int i = 0; i < 4; ++i) {
        int r = ty * 4 + i;
        int tr = trow[r];
        float s = 0.f, sm = 0.f;
        #pragma unroll
        for (int j = 0; j < 4; ++j) {
            float v = c[i][j];
            s += v;
            if (tcol[tx * 4 + j] == tr) sm += v;
        }
        atomicAdd(&redS[r], s);
        atomicAdd(&redSame[r], sm);
    }
    __syncthreads();
    if (tid < BM) {
        atomicAdd(&S[i0 + tid],    redS[tid]);
        atomicAdd(&SAME[i0 + tid], redSame[tid]);
    }
}

__global__ __launch_bounds__(128) void loss_kernel(
        const float* __restrict__ X, const int* __restrict__ T,
        const float* __restrict__ K, const float* __restrict__ colinv,
        double* __restrict__ acc) {
    const int row = blockIdx.x;
    const int tid = threadIdx.x;
    __shared__ float xs[EMB];
    *(float4*)&xs[tid * 4] = *(const float4*)&X[(size_t)row * EMB + tid * 4];
    __syncthreads();

    const int tgt = T[row];
    const int c = tid;
    float logit = -1e30f;
    if (c < NCLS) {
        float d = 0.f;
        #pragma unroll 4
        for (int k = 0; k < EMB; ++k) d = fmaf(K[k * NCLS + c], xs[k], d);
        float cosv = d * colinv[c];
        cosv = fminf(1.f, fmaxf(-1.f, cosv));
        logit = (cosv - (c == tgt ? BETA_F : 0.f)) * ALPHA_F;
    }

    __shared__ float rv[128];
    __shared__ int   ri[128];
    __shared__ float Lt;
    if (c == tgt) Lt = logit;

    rv[tid] = logit;
    __syncthreads();
    #pragma unroll
    for (int s = 64; s > 0; s >>= 1) {
        if (tid < s) rv[tid] = fmaxf(rv[tid], rv[tid + s]);
        __syncthreads();
    }
    const float m = rv[0];
    __syncthreads();

    rv[tid] = (c < NCLS) ? expf(logit - m) : 0.f;
    __syncthreads();
    #pragma unroll
    for (int s = 64; s > 0; s >>= 1) {
        if (tid < s) rv[tid] += rv[tid + s];
        __syncthreads();
    }
    const float lse = m + logf(rv[0]);
    __syncthreads();

    rv[tid] = logit;
    ri[tid] = (c < NCLS) ? c : 0x7fffffff;
    __syncthreads();
    #pragma unroll
    for (int s = 64; s > 0; s >>= 1) {
        if (tid < s) {
            float vo = rv[tid + s]; int io = ri[tid + s];
            if (vo > rv[tid] || (vo == rv[tid] && io < ri[tid])) { rv[tid] = vo; ri[tid] = io; }
        }
        __syncthreads();
    }

    if (tid == 0) {
        float loss_i = lse - Lt;
        atomicAdd(&acc[0], (double)loss_i);
        atomicAdd(&acc[1], (ri[0] == tgt) ? 1.0 : 0.0);
    }
}

__global__ void finalize_kernel(
        const float* __restrict__ X, const int* __restrict__ T,
        const int* __restrict__ hist, const float* __restrict__ S,
        const float* __restrict__ SAME, double* __restrict__ acc) {
    int r = blockIdx.x * blockDim.x + threadIdx.x;
    if (r >= NROWS) return;
    const float* x = X + (size_t)r * EMB;
    double d = 0.0;
    for (int k = 0; k < EMB; ++k) d = fma((double)x[k], (double)x[k], d);
    int h = hist[T[r]];
    float same = SAME[r];
    float pos_sum; int pos_cnt;
    if (d < 1.0) { pos_sum = same;            pos_cnt = h;     }
    else         { pos_sum = same - (float)d; pos_cnt = h - 1; }
    float neg_sum = S[r] - same;
    int   neg_cnt = NROWS - h;
    atomicAdd(&acc[2], (double)(pos_sum / (float)pos_cnt));
    atomicAdd(&acc[3], (double)(neg_sum / (float)neg_cnt));
}

__global__ void out_kernel(const double* __restrict__ acc, float* __restrict__ out) {
    if (threadIdx.x == 0) {
        out[0] = (float)(acc[0] / NROWS);
        out[1] = (float)(acc[1] / NROWS);
        out[2] = (float)(acc[2] / NROWS);
        out[3] = (float)(acc[3] / NROWS);
    }
}

extern "C" void kernel_launch(void* const* d_in, const int* in_sizes, int n_in,
                              void* d_out, int out_size, void* d_ws, size_t ws_size,
                              hipStream_t stream) {
    const float* X = (const float*)d_in[0];   // [8192, 512]
    const int*   T = (const int*)d_in[1];     // [8192]
    const float* K = (const float*)d_in[2];   // [512, 98]
    float* out = (float*)d_out;               // 4 scalars

    const size_t KBT_BYTES = (size_t)NCPAD * EMB * sizeof(unsigned short);  // 128 KB
    // misc block: acc(4 dbl) + posneg(128 dbl) + hist(100 int) + V(98*512 f) + usum(512 f)
    const size_t MISC_BYTES = 4 * 8 + 128 * 8 + 100 * 4
                            + (size_t)(NCLS * EMB + EMB) * 4;

    if (ws_size >= KBT_BYTES + MISC_BYTES + 256) {
        // fast path: class-sum factorization + fused MFMA logits/row-stats
        unsigned short* KbT = (unsigned short*)d_ws;
        char* misc = (char*)d_ws + KBT_BYTES;
        double* acc    = (double*)misc;
        double* posneg = acc + 4;
        int*    hist   = (int*)(posneg + 128);
        float*  V      = (float*)(hist + 100);
        float*  usum   = V + (size_t)NCLS * EMB;

        hipMemsetAsync(misc, 0, MISC_BYTES, stream);
        classsum_kernel<<<dim3(9, NROWS / CS_ROWS), 256, 0, stream>>>(X, T, K, V, usum, hist, KbT);
        main_kernel<<<NROWS / 16, 512, 0, stream>>>(X, KbT, T, hist, V, usum, acc, posneg);
        out2_kernel<<<1, 64, 0, stream>>>(acc, posneg, out);
    } else {
        // fallback: f32 path (small workspace)
        const size_t FB_BYTES = sizeof(double) * 4 + sizeof(int) * NCLS
                              + sizeof(float) * (NCLS + 2 * NROWS);
        double* acc    = (double*)d_ws;
        int*    hist   = (int*)(acc + 4);
        float*  colinv = (float*)(hist + NCLS);
        float*  S      = colinv + NCLS;
        float*  SAME   = S + NROWS;

        hipMemsetAsync(d_ws, 0, FB_BYTES, stream);
        hist_kernel<<<(NROWS + 255) / 256, 256, 0, stream>>>(T, hist);
        colnorm_kernel<<<NCLS, 64, 0, stream>>>(K, colinv);
        simred_kernel<<<dim3(NROWS / BM, NROWS / BN), 256, 0, stream>>>(X, T, S, SAME);
        loss_kernel<<<NROWS, 128, 0, stream>>>(X, T, K, colinv, acc);
        finalize_kernel<<<(NROWS + 255) / 256, 256, 0, stream>>>(X, T, hist, S, SAME, acc);
        out_kernel<<<1, 64, 0, stream>>>(acc, out);
    }
}

// Round 8
// 63.412 us; speedup vs baseline: 1.5641x; 1.2607x over previous
//
#include <hip/hip_runtime.h>
#include <hip/hip_bf16.h>

typedef __attribute__((ext_vector_type(8))) short bf16x8;
typedef __attribute__((ext_vector_type(4))) float f32x4;

#define NROWS 8192
#define EMB   512
#define NCLS  98
#define NCPAD 128
#define MAXPER 256
#define ALPHA_F 10.0f
#define BETA_F  2.0f

__device__ __forceinline__ unsigned short f2bf(float x) {
    unsigned u = __builtin_bit_cast(unsigned, x);
    u += 0x7FFF + ((u >> 16) & 1);
    return (unsigned short)(u >> 16);
}

// ---------------- scatter rows into class buckets + kprep (fused) ----------------
// blocks 0..31: counting-sort scatter; blocks 32..63: KbT[c][k]=bf16(K[k][c]/||K[:,c]||)
__global__ __launch_bounds__(256) void scatter_kernel(
        const int* __restrict__ T, const float* __restrict__ K,
        int* __restrict__ cnt, int* __restrict__ bucket,
        unsigned short* __restrict__ KbT) {
    const int tid = threadIdx.x;
    const int bid = blockIdx.x;
    const int lane = tid & 63, w = tid >> 6;

    if (bid < 32) {
        int i = bid * 256 + tid;
        int t = T[i];
        int slot = atomicAdd(&cnt[t], 1);
        if (slot < MAXPER) bucket[t * MAXPER + slot] = i;
        return;
    }
    // kprep: one class per wave
    int c = (bid - 32) * 4 + w;              // 0..127
    if (c < NCLS) {
        float v[8]; float s = 0.f;
        #pragma unroll
        for (int q = 0; q < 8; ++q) {
            float x = K[(size_t)(lane + q * 64) * NCLS + c];
            v[q] = x; s = fmaf(x, x, s);
        }
        #pragma unroll
        for (int d = 32; d > 0; d >>= 1) s += __shfl_xor(s, d);
        float inv = 1.0f / sqrtf(s);
        #pragma unroll
        for (int q = 0; q < 8; ++q)
            KbT[(size_t)c * EMB + lane + q * 64] = f2bf(v[q] * inv);
    } else {
        #pragma unroll
        for (int q = 0; q < 8; ++q)
            KbT[(size_t)c * EMB + lane + q * 64] = 0;
    }
}

// ---------------- V[c][k] = sum over bucket c of X[row][k]; usum accumulated ----------------
// grid (8, 98): one wave per (dim-chunk, class); contention-free direct writes
__global__ __launch_bounds__(64) void classv_kernel(
        const float* __restrict__ X, const int* __restrict__ cnt,
        const int* __restrict__ bucket,
        float* __restrict__ V, float* __restrict__ usum) {
    const int lane = threadIdx.x;
    const int c = blockIdx.y;
    const int d0 = blockIdx.x * 64;
    const int n = cnt[c];
    const int* bk = bucket + c * MAXPER;
    float a = 0.f;
    #pragma unroll 4
    for (int j = 0; j < n; ++j) {
        int row = bk[j];                               // wave-uniform
        a += X[(size_t)row * EMB + d0 + lane];         // 256B coalesced per row
    }
    V[(size_t)c * EMB + d0 + lane] = a;
    atomicAdd(&usum[d0 + lane], a);                    // 98-way, 512 addrs: cheap
}

// ---------------- fused main: 8 waves per 16 rows, K-split by wave ----------------
// wave w owns dims [w*64, w*64+64); lane (c0,g): row row0+c0, dim sub-block g*8
__global__ __launch_bounds__(512) void main_kernel(
        const float* __restrict__ X, const unsigned short* __restrict__ KbT,
        const int* __restrict__ T, const int* __restrict__ hist,
        const float* __restrict__ V, const float* __restrict__ usum,
        double* __restrict__ acc, double* __restrict__ posneg) {
    __shared__ f32x4  redAV[4][8][64];        // 32 KB, two-stage reuse
    __shared__ float  redS[8][16], redSM[8][16];
    __shared__ double redD[8][16];

    const int row0 = blockIdx.x * 16;
    const int tid = threadIdx.x;
    const int w = tid >> 6, lane = tid & 63;
    const int c0 = lane & 15, g = lane >> 4;
    const int myrow = row0 + c0;
    const int tmy = T[myrow];
    const float* vrow = V + (size_t)tmy * EMB;

    f32x4 av[8] = {};
    float s = 0.f, sm = 0.f; double d = 0.0;

    #pragma unroll
    for (int t = 0; t < 2; ++t) {
        const int kk = w * 64 + t * 32;
        const float* xp = &X[(size_t)myrow * EMB + kk + g * 8];
        float4 x0 = *(const float4*)xp, x1 = *(const float4*)(xp + 4);
        const float* up = &usum[kk + g * 8];
        float4 u0 = *(const float4*)up, u1 = *(const float4*)(up + 4);
        const float* vp = &vrow[kk + g * 8];
        float4 v0 = *(const float4*)vp, v1 = *(const float4*)(vp + 4);

        float xf[8] = {x0.x, x0.y, x0.z, x0.w, x1.x, x1.y, x1.z, x1.w};
        float uf[8] = {u0.x, u0.y, u0.z, u0.w, u1.x, u1.y, u1.z, u1.w};
        float vf[8] = {v0.x, v0.y, v0.z, v0.w, v1.x, v1.y, v1.z, v1.w};

        bf16x8 a;
        #pragma unroll
        for (int j = 0; j < 8; ++j) {
            s  = fmaf(xf[j], uf[j], s);
            sm = fmaf(xf[j], vf[j], sm);
            d  = fma((double)xf[j], (double)xf[j], d);
            a[j] = (short)f2bf(xf[j]);
        }
        #pragma unroll
        for (int f = 0; f < 8; ++f) {
            bf16x8 b = *(const bf16x8*)&KbT[(size_t)(f * 16 + c0) * EMB + kk + g * 8];
            av[f] = __builtin_amdgcn_mfma_f32_16x16x32_bf16(a, b, av[f], 0, 0, 0);
        }
    }

    // intra-wave reduce of s/sm/d over the 4 g-groups
    s  += __shfl_xor(s, 16);  s  += __shfl_xor(s, 32);
    sm += __shfl_xor(sm, 16); sm += __shfl_xor(sm, 32);
    d  += __shfl_xor(d, 16);  d  += __shfl_xor(d, 32);
    if (g == 0) { redS[w][c0] = s; redSM[w][c0] = sm; redD[w][c0] = d; }

    // cross-wave reduce of av: 8 -> 4 -> 1 via LDS (two stages, slots reused)
    if (w >= 4) {
        #pragma unroll
        for (int f = 0; f < 8; ++f) redAV[w - 4][f][lane] = av[f];
    }
    __syncthreads();
    if (w < 4) {
        #pragma unroll
        for (int f = 0; f < 8; ++f) av[f] += redAV[w][f][lane];
    }
    __syncthreads();
    if (w >= 1 && w < 4) {
        #pragma unroll
        for (int f = 0; f < 8; ++f) redAV[w - 1][f][lane] = av[f];
    }
    __syncthreads();
    if (w != 0) return;

    #pragma unroll
    for (int f = 0; f < 8; ++f) {
        av[f] += redAV[0][f][lane];
        av[f] += redAV[1][f][lane];
        av[f] += redAV[2][f][lane];
    }
    if (g == 0) {
        #pragma unroll
        for (int ww = 1; ww < 8; ++ww) {
            s += redS[ww][c0]; sm += redSM[ww][c0]; d += redD[ww][c0];
        }
    }

    // ---- per-row pos/neg contributions (g==0 lanes own rows) ----
    double pc = 0.0, nc = 0.0;
    if (g == 0) {
        int h = hist[tmy];
        float pos_sum; int pos_cnt;
        if (d < 1.0) { pos_sum = sm;            pos_cnt = h;     }
        else         { pos_sum = sm - (float)d; pos_cnt = h - 1; }
        float neg_sum = s - sm;
        pc = (double)(pos_sum / (float)pos_cnt);
        nc = (double)(neg_sum / (float)(NROWS - h));
    }
    #pragma unroll
    for (int m = 1; m < 16; m <<= 1) { pc += __shfl_xor(pc, m); nc += __shfl_xor(nc, m); }
    if (lane == 0) {
        int b = (blockIdx.x & 63) * 2;
        atomicAdd(&posneg[b],     pc);
        atomicAdd(&posneg[b + 1], nc);
    }

    // ---- logits epilogue: softmax / argmax / loss ----
    float lossacc = 0.f, pracc = 0.f;
    #pragma unroll
    for (int r = 0; r < 4; ++r) {
        const int row = row0 + g * 4 + r;
        const int tgt = T[row];
        float vals[8];
        float m = -1e30f;
        #pragma unroll
        for (int f = 0; f < 8; ++f) {
            int col = f * 16 + c0;
            float cosv = fminf(1.f, fmaxf(-1.f, av[f][r]));
            float logit = (cosv - (col == tgt ? BETA_F : 0.f)) * ALPHA_F;
            if (col >= NCLS) logit = -1e30f;
            vals[f] = logit;
            m = fmaxf(m, logit);
        }
        #pragma unroll
        for (int dd = 1; dd < 16; dd <<= 1) m = fmaxf(m, __shfl_xor(m, dd));

        float se = 0.f, tval = -1e30f;
        float bv = -1e30f; int bi = 0x7fffffff;
        #pragma unroll
        for (int f = 0; f < 8; ++f) {
            int col = f * 16 + c0;
            se += __expf(vals[f] - m) * (col < NCLS ? 1.f : 0.f);
            if (col == tgt) tval = vals[f];
            if (vals[f] > bv) { bv = vals[f]; bi = col; }
        }
        #pragma unroll
        for (int dd = 1; dd < 16; dd <<= 1) {
            se += __shfl_xor(se, dd);
            tval = fmaxf(tval, __shfl_xor(tval, dd));
            float ov = __shfl_xor(bv, dd); int oi = __shfl_xor(bi, dd);
            if (ov > bv || (ov == bv && oi < bi)) { bv = ov; bi = oi; }
        }
        if (c0 == 0) {
            lossacc += (m + logf(se)) - tval;
            pracc += (bi == tgt) ? 1.f : 0.f;
        }
    }
    lossacc += __shfl_xor(lossacc, 16); lossacc += __shfl_xor(lossacc, 32);
    pracc   += __shfl_xor(pracc, 16);   pracc   += __shfl_xor(pracc, 32);
    if (lane == 0) {
        atomicAdd(&acc[0], (double)lossacc);
        atomicAdd(&acc[1], (double)pracc);
    }
}

__global__ void out2_kernel(const double* __restrict__ acc,
                            const double* __restrict__ posneg,
                            float* __restrict__ out) {
    if (threadIdx.x == 0) {
        double p = 0.0, n = 0.0;
        for (int i = 0; i < 64; ++i) { p += posneg[i * 2]; n += posneg[i * 2 + 1]; }
        out[0] = (float)(acc[0] / NROWS);
        out[1] = (float)(acc[1] / NROWS);
        out[2] = (float)(p / NROWS);
        out[3] = (float)(n / NROWS);
    }
}

// ================= fallback f32 path (tiny workspace) =================
#define BM 64
#define BN 64
#define BK 32
#define LDA 68

__global__ void hist_kernel(const int* __restrict__ t, int* __restrict__ hist) {
    int i = blockIdx.x * blockDim.x + threadIdx.x;
    if (i < NROWS) atomicAdd(&hist[t[i]], 1);
}

__global__ void colnorm_kernel(const float* __restrict__ K, float* __restrict__ colinv) {
    int c = blockIdx.x;
    float s = 0.f;
    for (int k = threadIdx.x; k < EMB; k += 64) {
        float v = K[k * NCLS + c];
        s = fmaf(v, v, s);
    }
    #pragma unroll
    for (int off = 32; off > 0; off >>= 1) s += __shfl_down(s, off);
    if (threadIdx.x == 0) colinv[c] = 1.0f / sqrtf(s);
}

__global__ __launch_bounds__(256) void simred_kernel(
        const float* __restrict__ X, const int* __restrict__ T,
        float* __restrict__ S, float* __restrict__ SAME) {
    __shared__ float As[BK * LDA];
    __shared__ float Bs[BK * LDA];
    __shared__ int   trow[BM], tcol[BN];
    __shared__ float redS[BM], redSame[BM];

    const int tid = threadIdx.x;
    const int tx = tid & 15, ty = tid >> 4;
    const int i0 = blockIdx.x * BM, j0 = blockIdx.y * BN;

    if (tid < BM) {
        trow[tid] = T[i0 + tid];
        tcol[tid] = T[j0 + tid];
        redS[tid] = 0.f;
        redSame[tid] = 0.f;
    }

    float c[4][4] = {};
    for (int kk = 0; kk < EMB; kk += BK) {
        #pragma unroll
        for (int q = 0; q < 2; ++q) {
            int l  = tid * 2 + q;
            int r  = l >> 3;
            int kq = (l & 7) << 2;
            const float4 va = *(const float4*)(X + (size_t)(i0 + r) * EMB + kk + kq);
            As[(kq + 0) * LDA + r] = va.x;
            As[(kq + 1) * LDA + r] = va.y;
            As[(kq + 2) * LDA + r] = va.z;
            As[(kq + 3) * LDA + r] = va.w;
            const float4 vb = *(const float4*)(X + (size_t)(j0 + r) * EMB + kk + kq);
            Bs[(kq + 0) * LDA + r] = vb.x;
            Bs[(kq + 1) * LDA + r] = vb.y;
            Bs[(kq + 2) * LDA + r] = vb.z;
            Bs[(kq + 3) * LDA + r] = vb.w;
        }
        __syncthreads();
        #pragma unroll
        for (int k = 0; k < BK; ++k) {
            float4 a4 = *(const float4*)&As[k * LDA + ty * 4];
            float4 b4 = *(const float4*)&Bs[k * LDA + tx * 4];
            float a[4] = {a4.x, a4.y, a4.z, a4.w};
            float b[4] = {b4.x, b4.y, b4.z, b4.w};
            #pragma unroll
            for (int i = 0; i < 4; ++i)
                #pragma unroll
                for (int j = 0; j < 4; ++j)
                    c[i][j] = fmaf(a[i], b[j], c[i][j]);
        }
        __syncthreads();
    }

    #pragma unroll
    for (int i = 0; i < 4; ++i) {
        int r = ty * 4 + i;
        int tr = trow[r];
        float s = 0.f, sm = 0.f;
        #pragma unroll
        for (int j = 0; j < 4; ++j) {
            float v = c[i][j];
            s += v;
            if (tcol[tx * 4 + j] == tr) sm += v;
        }
        atomicAdd(&redS[r], s);
        atomicAdd(&redSame[r], sm);
    }
    __syncthreads();
    if (tid < BM) {
        atomicAdd(&S[i0 + tid],    redS[tid]);
        atomicAdd(&SAME[i0 + tid], redSame[tid]);
    }
}

__global__ __launch_bounds__(128) void loss_kernel(
        const float* __restrict__ X, const int* __restrict__ T,
        const float* __restrict__ K, const float* __restrict__ colinv,
        double* __restrict__ acc) {
    const int row = blockIdx.x;
    const int tid = threadIdx.x;
    __shared__ float xs[EMB];
    *(float4*)&xs[tid * 4] = *(const float4*)&X[(size_t)row * EMB + tid * 4];
    __syncthreads();

    const int tgt = T[row];
    const int c = tid;
    float logit = -1e30f;
    if (c < NCLS) {
        float d = 0.f;
        #pragma unroll 4
        for (int k = 0; k < EMB; ++k) d = fmaf(K[k * NCLS + c], xs[k], d);
        float cosv = d * colinv[c];
        cosv = fminf(1.f, fmaxf(-1.f, cosv));
        logit = (cosv - (c == tgt ? BETA_F : 0.f)) * ALPHA_F;
    }

    __shared__ float rv[128];
    __shared__ int   ri[128];
    __shared__ float Lt;
    if (c == tgt) Lt = logit;

    rv[tid] = logit;
    __syncthreads();
    #pragma unroll
    for (int s = 64; s > 0; s >>= 1) {
        if (tid < s) rv[tid] = fmaxf(rv[tid], rv[tid + s]);
        __syncthreads();
    }
    const float m = rv[0];
    __syncthreads();

    rv[tid] = (c < NCLS) ? expf(logit - m) : 0.f;
    __syncthreads();
    #pragma unroll
    for (int s = 64; s > 0; s >>= 1) {
        if (tid < s) rv[tid] += rv[tid + s];
        __syncthreads();
    }
    const float lse = m + logf(rv[0]);
    __syncthreads();

    rv[tid] = logit;
    ri[tid] = (c < NCLS) ? c : 0x7fffffff;
    __syncthreads();
    #pragma unroll
    for (int s = 64; s > 0; s >>= 1) {
        if (tid < s) {
            float vo = rv[tid + s]; int io = ri[tid + s];
            if (vo > rv[tid] || (vo == rv[tid] && io < ri[tid])) { rv[tid] = vo; ri[tid] = io; }
        }
        __syncthreads();
    }

    if (tid == 0) {
        float loss_i = lse - Lt;
        atomicAdd(&acc[0], (double)loss_i);
        atomicAdd(&acc[1], (ri[0] == tgt) ? 1.0 : 0.0);
    }
}

__global__ void finalize_kernel(
        const float* __restrict__ X, const int* __restrict__ T,
        const int* __restrict__ hist, const float* __restrict__ S,
        const float* __restrict__ SAME, double* __restrict__ acc) {
    int r = blockIdx.x * blockDim.x + threadIdx.x;
    if (r >= NROWS) return;
    const float* x = X + (size_t)r * EMB;
    double d = 0.0;
    for (int k = 0; k < EMB; ++k) d = fma((double)x[k], (double)x[k], d);
    int h = hist[T[r]];
    float same = SAME[r];
    float pos_sum; int pos_cnt;
    if (d < 1.0) { pos_sum = same;            pos_cnt = h;     }
    else         { pos_sum = same - (float)d; pos_cnt = h - 1; }
    float neg_sum = S[r] - same;
    int   neg_cnt = NROWS - h;
    atomicAdd(&acc[2], (double)(pos_sum / (float)pos_cnt));
    atomicAdd(&acc[3], (double)(neg_sum / (float)neg_cnt));
}

__global__ void out_kernel(const double* __restrict__ acc, float* __restrict__ out) {
    if (threadIdx.x == 0) {
        out[0] = (float)(acc[0] / NROWS);
        out[1] = (float)(acc[1] / NROWS);
        out[2] = (float)(acc[2] / NROWS);
        out[3] = (float)(acc[3] / NROWS);
    }
}

extern "C" void kernel_launch(void* const* d_in, const int* in_sizes, int n_in,
                              void* d_out, int out_size, void* d_ws, size_t ws_size,
                              hipStream_t stream) {
    const float* X = (const float*)d_in[0];   // [8192, 512]
    const int*   T = (const int*)d_in[1];     // [8192]
    const float* K = (const float*)d_in[2];   // [512, 98]
    float* out = (float*)d_out;               // 4 scalars

    const size_t KBT_BYTES    = (size_t)NCPAD * EMB * sizeof(unsigned short); // 128 KB
    const size_t V_BYTES      = (size_t)NCLS * EMB * sizeof(float);           // 200704 B
    const size_t BUCKET_BYTES = (size_t)NCLS * MAXPER * sizeof(int);          // 100352 B
    // zeroed zone: acc(4 dbl) + posneg(128 dbl) + cnt(128 int) + usum(512 f)
    const size_t ZERO_BYTES   = 4 * 8 + 128 * 8 + 128 * 4 + 512 * 4;          // 3616 B

    if (ws_size >= KBT_BYTES + V_BYTES + BUCKET_BYTES + ZERO_BYTES + 256) {
        unsigned short* KbT = (unsigned short*)d_ws;
        float* V      = (float*)((char*)d_ws + KBT_BYTES);
        int*   bucket = (int*)((char*)d_ws + KBT_BYTES + V_BYTES);
        char*  zz     = (char*)d_ws + KBT_BYTES + V_BYTES + BUCKET_BYTES;
        double* acc    = (double*)zz;
        double* posneg = acc + 4;
        int*    cnt    = (int*)(posneg + 128);
        float*  usum   = (float*)(cnt + 128);

        hipMemsetAsync(zz, 0, ZERO_BYTES, stream);
        scatter_kernel<<<64, 256, 0, stream>>>(T, K, cnt, bucket, KbT);
        classv_kernel<<<dim3(8, NCLS), 64, 0, stream>>>(X, cnt, bucket, V, usum);
        main_kernel<<<NROWS / 16, 512, 0, stream>>>(X, KbT, T, cnt, V, usum, acc, posneg);
        out2_kernel<<<1, 64, 0, stream>>>(acc, posneg, out);
    } else {
        // fallback: f32 path (small workspace)
        const size_t FB_BYTES = sizeof(double) * 4 + sizeof(int) * NCLS
                              + sizeof(float) * (NCLS + 2 * NROWS);
        double* acc    = (double*)d_ws;
        int*    hist   = (int*)(acc + 4);
        float*  colinv = (float*)(hist + NCLS);
        float*  S      = colinv + NCLS;
        float*  SAME   = S + NROWS;

        hipMemsetAsync(d_ws, 0, FB_BYTES, stream);
        hist_kernel<<<(NROWS + 255) / 256, 256, 0, stream>>>(T, hist);
        colnorm_kernel<<<NCLS, 64, 0, stream>>>(K, colinv);
        simred_kernel<<<dim3(NROWS / BM, NROWS / BN), 256, 0, stream>>>(X, T, S, SAME);
        loss_kernel<<<NROWS, 128, 0, stream>>>(X, T, K, colinv, acc);
        finalize_kernel<<<(NROWS + 255) / 256, 256, 0, stream>>>(X, T, hist, S, SAME, acc);
        out_kernel<<<1, 64, 0, stream>>>(acc, out);
    }
}

// Round 9
// 57.710 us; speedup vs baseline: 1.7187x; 1.0988x over previous
//
#include <hip/hip_runtime.h>
#include <hip/hip_bf16.h>

typedef __attribute__((ext_vector_type(8))) short bf16x8;
typedef __attribute__((ext_vector_type(4))) float f32x4;

#define NROWS 8192
#define EMB   512
#define NCLS  98
#define NCPAD 128
#define MAXPER 256
#define ALPHA_F 10.0f
#define BETA_F  2.0f

__device__ __forceinline__ unsigned short f2bf(float x) {
    unsigned u = __builtin_bit_cast(unsigned, x);
    u += 0x7FFF + ((u >> 16) & 1);
    return (unsigned short)(u >> 16);
}

// ---------------- single-block: zero accumulators + counting-sort scatter ----------------
__global__ __launch_bounds__(1024) void init_scatter_kernel(
        const int* __restrict__ T, int* __restrict__ cnt, int* __restrict__ bucket,
        double* __restrict__ acc, double* __restrict__ posneg, float* __restrict__ usum) {
    __shared__ int lh[NCLS];
    const int tid = threadIdx.x;
    if (tid < NCLS) lh[tid] = 0;
    if (tid < 4)   acc[tid] = 0.0;
    if (tid < 128) posneg[tid] = 0.0;
    if (tid < EMB) usum[tid] = 0.f;
    __syncthreads();
    #pragma unroll
    for (int k = 0; k < NROWS / 1024; ++k) {
        int i = k * 1024 + tid;
        int t = T[i];
        int slot = atomicAdd(&lh[t], 1);
        if (slot < MAXPER) bucket[t * MAXPER + slot] = i;
    }
    __syncthreads();
    if (tid < NCLS) cnt[tid] = lh[tid];
}

// ---------------- V[c][k] = bucket-sum of X; usum accumulated; kprep rides along ----------
// grid 816: bx<784 -> (class=bx>>3, dimchunk=bx&7), 4 waves split rows; bx>=784 -> kprep
__global__ __launch_bounds__(256) void classv_kernel(
        const float* __restrict__ X, const float* __restrict__ K,
        const int* __restrict__ cnt, const int* __restrict__ bucket,
        float* __restrict__ V, float* __restrict__ usum,
        unsigned short* __restrict__ KbT) {
    const int tid = threadIdx.x;
    const int lane = tid & 63, w = tid >> 6;
    const int bx = blockIdx.x;

    if (bx >= 784) {
        // kprep: KbT[c][k] = bf16(K[k][c]/||K[:,c]||), one class per wave
        int c = (bx - 784) * 4 + w;            // 0..127
        if (c < NCLS) {
            float v[8]; float s = 0.f;
            #pragma unroll
            for (int q = 0; q < 8; ++q) {
                float x = K[(size_t)(lane + q * 64) * NCLS + c];
                v[q] = x; s = fmaf(x, x, s);
            }
            #pragma unroll
            for (int d = 32; d > 0; d >>= 1) s += __shfl_xor(s, d);
            float inv = 1.0f / sqrtf(s);
            #pragma unroll
            for (int q = 0; q < 8; ++q)
                KbT[(size_t)c * EMB + lane + q * 64] = f2bf(v[q] * inv);
        } else {
            #pragma unroll
            for (int q = 0; q < 8; ++q)
                KbT[(size_t)c * EMB + lane + q * 64] = 0;
        }
        return;
    }

    __shared__ float red[3][64];
    const int c = bx >> 3, d0 = (bx & 7) * 64;
    int n = cnt[c]; if (n > MAXPER) n = MAXPER;
    const int* bk = bucket + c * MAXPER;
    float a = 0.f;
    for (int j = w; j < n; j += 4) {
        int row = bk[j];                               // wave-uniform
        a += X[(size_t)row * EMB + d0 + lane];         // 256B coalesced per row
    }
    if (w > 0) red[w - 1][lane] = a;
    __syncthreads();
    if (w == 0) {
        a += red[0][lane] + red[1][lane] + red[2][lane];
        V[(size_t)c * EMB + d0 + lane] = a;
        atomicAdd(&usum[d0 + lane], a);                // 98-way per address: cheap
    }
}

// ---------------- fused main: 8 waves per 16 rows, K-split by wave ----------------
// wave w owns dims [w*64, w*64+64); lane (c0,g): row row0+c0, dim sub-block g*8
__global__ __launch_bounds__(512) void main_kernel(
        const float* __restrict__ X, const unsigned short* __restrict__ KbT,
        const int* __restrict__ T, const int* __restrict__ hist,
        const float* __restrict__ V, const float* __restrict__ usum,
        double* __restrict__ acc, double* __restrict__ posneg) {
    __shared__ f32x4  redAV[4][8][64];        // 32 KB, two-stage reuse
    __shared__ float  redS[8][16], redSM[8][16];
    __shared__ double redD[8][16];

    const int row0 = blockIdx.x * 16;
    const int tid = threadIdx.x;
    const int w = tid >> 6, lane = tid & 63;
    const int c0 = lane & 15, g = lane >> 4;
    const int myrow = row0 + c0;
    const int tmy = T[myrow];
    const float* vrow = V + (size_t)tmy * EMB;

    f32x4 av[8] = {};
    float s = 0.f, sm = 0.f; double d = 0.0;

    #pragma unroll
    for (int t = 0; t < 2; ++t) {
        const int kk = w * 64 + t * 32;
        const float* xp = &X[(size_t)myrow * EMB + kk + g * 8];
        float4 x0 = *(const float4*)xp, x1 = *(const float4*)(xp + 4);
        const float* up = &usum[kk + g * 8];
        float4 u0 = *(const float4*)up, u1 = *(const float4*)(up + 4);
        const float* vp = &vrow[kk + g * 8];
        float4 v0 = *(const float4*)vp, v1 = *(const float4*)(vp + 4);

        float xf[8] = {x0.x, x0.y, x0.z, x0.w, x1.x, x1.y, x1.z, x1.w};
        float uf[8] = {u0.x, u0.y, u0.z, u0.w, u1.x, u1.y, u1.z, u1.w};
        float vf[8] = {v0.x, v0.y, v0.z, v0.w, v1.x, v1.y, v1.z, v1.w};

        bf16x8 a;
        #pragma unroll
        for (int j = 0; j < 8; ++j) {
            s  = fmaf(xf[j], uf[j], s);
            sm = fmaf(xf[j], vf[j], sm);
            d  = fma((double)xf[j], (double)xf[j], d);
            a[j] = (short)f2bf(xf[j]);
        }
        #pragma unroll
        for (int f = 0; f < 8; ++f) {
            bf16x8 b = *(const bf16x8*)&KbT[(size_t)(f * 16 + c0) * EMB + kk + g * 8];
            av[f] = __builtin_amdgcn_mfma_f32_16x16x32_bf16(a, b, av[f], 0, 0, 0);
        }
    }

    // intra-wave reduce of s/sm/d over the 4 g-groups
    s  += __shfl_xor(s, 16);  s  += __shfl_xor(s, 32);
    sm += __shfl_xor(sm, 16); sm += __shfl_xor(sm, 32);
    d  += __shfl_xor(d, 16);  d  += __shfl_xor(d, 32);
    if (g == 0) { redS[w][c0] = s; redSM[w][c0] = sm; redD[w][c0] = d; }

    // cross-wave reduce of av: 8 -> 4 -> 1 via LDS (two stages, slots reused)
    if (w >= 4) {
        #pragma unroll
        for (int f = 0; f < 8; ++f) redAV[w - 4][f][lane] = av[f];
    }
    __syncthreads();
    if (w < 4) {
        #pragma unroll
        for (int f = 0; f < 8; ++f) av[f] += redAV[w][f][lane];
    }
    __syncthreads();
    if (w >= 1 && w < 4) {
        #pragma unroll
        for (int f = 0; f < 8; ++f) redAV[w - 1][f][lane] = av[f];
    }
    __syncthreads();
    if (w != 0) return;

    #pragma unroll
    for (int f = 0; f < 8; ++f) {
        av[f] += redAV[0][f][lane];
        av[f] += redAV[1][f][lane];
        av[f] += redAV[2][f][lane];
    }
    if (g == 0) {
        #pragma unroll
        for (int ww = 1; ww < 8; ++ww) {
            s += redS[ww][c0]; sm += redSM[ww][c0]; d += redD[ww][c0];
        }
    }

    // ---- per-row pos/neg contributions (g==0 lanes own rows) ----
    double pc = 0.0, nc = 0.0;
    if (g == 0) {
        int h = hist[tmy];
        float pos_sum; int pos_cnt;
        if (d < 1.0) { pos_sum = sm;            pos_cnt = h;     }
        else         { pos_sum = sm - (float)d; pos_cnt = h - 1; }
        float neg_sum = s - sm;
        pc = (double)(pos_sum / (float)pos_cnt);
        nc = (double)(neg_sum / (float)(NROWS - h));
    }
    #pragma unroll
    for (int m = 1; m < 16; m <<= 1) { pc += __shfl_xor(pc, m); nc += __shfl_xor(nc, m); }
    if (lane == 0) {
        int b = (blockIdx.x & 63) * 2;
        atomicAdd(&posneg[b],     pc);
        atomicAdd(&posneg[b + 1], nc);
    }

    // ---- logits epilogue: softmax / argmax / loss ----
    float lossacc = 0.f, pracc = 0.f;
    #pragma unroll
    for (int r = 0; r < 4; ++r) {
        const int row = row0 + g * 4 + r;
        const int tgt = T[row];
        float vals[8];
        float m = -1e30f;
        #pragma unroll
        for (int f = 0; f < 8; ++f) {
            int col = f * 16 + c0;
            float cosv = fminf(1.f, fmaxf(-1.f, av[f][r]));
            float logit = (cosv - (col == tgt ? BETA_F : 0.f)) * ALPHA_F;
            if (col >= NCLS) logit = -1e30f;
            vals[f] = logit;
            m = fmaxf(m, logit);
        }
        #pragma unroll
        for (int dd = 1; dd < 16; dd <<= 1) m = fmaxf(m, __shfl_xor(m, dd));

        float se = 0.f, tval = -1e30f;
        float bv = -1e30f; int bi = 0x7fffffff;
        #pragma unroll
        for (int f = 0; f < 8; ++f) {
            int col = f * 16 + c0;
            se += __expf(vals[f] - m) * (col < NCLS ? 1.f : 0.f);
            if (col == tgt) tval = vals[f];
            if (vals[f] > bv) { bv = vals[f]; bi = col; }
        }
        #pragma unroll
        for (int dd = 1; dd < 16; dd <<= 1) {
            se += __shfl_xor(se, dd);
            tval = fmaxf(tval, __shfl_xor(tval, dd));
            float ov = __shfl_xor(bv, dd); int oi = __shfl_xor(bi, dd);
            if (ov > bv || (ov == bv && oi < bi)) { bv = ov; bi = oi; }
        }
        if (c0 == 0) {
            lossacc += (m + logf(se)) - tval;
            pracc += (bi == tgt) ? 1.f : 0.f;
        }
    }
    lossacc += __shfl_xor(lossacc, 16); lossacc += __shfl_xor(lossacc, 32);
    pracc   += __shfl_xor(pracc, 16);   pracc   += __shfl_xor(pracc, 32);
    if (lane == 0) {
        atomicAdd(&acc[0], (double)lossacc);
        atomicAdd(&acc[1], (double)pracc);
    }
}

__global__ void out2_kernel(const double* __restrict__ acc,
                            const double* __restrict__ posneg,
                            float* __restrict__ out) {
    if (threadIdx.x == 0) {
        double p = 0.0, n = 0.0;
        for (int i = 0; i < 64; ++i) { p += posneg[i * 2]; n += posneg[i * 2 + 1]; }
        out[0] = (float)(acc[0] / NROWS);
        out[1] = (float)(acc[1] / NROWS);
        out[2] = (float)(p / NROWS);
        out[3] = (float)(n / NROWS);
    }
}

// ================= fallback f32 path (tiny workspace) =================
#define BM 64
#define BN 64
#define BK 32
#define LDA 68

__global__ void hist_kernel(const int* __restrict__ t, int* __restrict__ hist) {
    int i = blockIdx.x * blockDim.x + threadIdx.x;
    if (i < NROWS) atomicAdd(&hist[t[i]], 1);
}

__global__ void colnorm_kernel(const float* __restrict__ K, float* __restrict__ colinv) {
    int c = blockIdx.x;
    float s = 0.f;
    for (int k = threadIdx.x; k < EMB; k += 64) {
        float v = K[k * NCLS + c];
        s = fmaf(v, v, s);
    }
    #pragma unroll
    for (int off = 32; off > 0; off >>= 1) s += __shfl_down(s, off);
    if (threadIdx.x == 0) colinv[c] = 1.0f / sqrtf(s);
}

__global__ __launch_bounds__(256) void simred_kernel(
        const float* __restrict__ X, const int* __restrict__ T,
        float* __restrict__ S, float* __restrict__ SAME) {
    __shared__ float As[BK * LDA];
    __shared__ float Bs[BK * LDA];
    __shared__ int   trow[BM], tcol[BN];
    __shared__ float redS[BM], redSame[BM];

    const int tid = threadIdx.x;
    const int tx = tid & 15, ty = tid >> 4;
    const int i0 = blockIdx.x * BM, j0 = blockIdx.y * BN;

    if (tid < BM) {
        trow[tid] = T[i0 + tid];
        tcol[tid] = T[j0 + tid];
        redS[tid] = 0.f;
        redSame[tid] = 0.f;
    }

    float c[4][4] = {};
    for (int kk = 0; kk < EMB; kk += BK) {
        #pragma unroll
        for (int q = 0; q < 2; ++q) {
            int l  = tid * 2 + q;
            int r  = l >> 3;
            int kq = (l & 7) << 2;
            const float4 va = *(const float4*)(X + (size_t)(i0 + r) * EMB + kk + kq);
            As[(kq + 0) * LDA + r] = va.x;
            As[(kq + 1) * LDA + r] = va.y;
            As[(kq + 2) * LDA + r] = va.z;
            As[(kq + 3) * LDA + r] = va.w;
            const float4 vb = *(const float4*)(X + (size_t)(j0 + r) * EMB + kk + kq);
            Bs[(kq + 0) * LDA + r] = vb.x;
            Bs[(kq + 1) * LDA + r] = vb.y;
            Bs[(kq + 2) * LDA + r] = vb.z;
            Bs[(kq + 3) * LDA + r] = vb.w;
        }
        __syncthreads();
        #pragma unroll
        for (int k = 0; k < BK; ++k) {
            float4 a4 = *(const float4*)&As[k * LDA + ty * 4];
            float4 b4 = *(const float4*)&Bs[k * LDA + tx * 4];
            float a[4] = {a4.x, a4.y, a4.z, a4.w};
            float b[4] = {b4.x, b4.y, b4.z, b4.w};
            #pragma unroll
            for (int i = 0; i < 4; ++i)
                #pragma unroll
                for (int j = 0; j < 4; ++j)
                    c[i][j] = fmaf(a[i], b[j], c[i][j]);
        }
        __syncthreads();
    }

    #pragma unroll
    for (int i = 0; i < 4; ++i) {
        int r = ty * 4 + i;
        int tr = trow[r];
        float s = 0.f, sm = 0.f;
        #pragma unroll
        for (int j = 0; j < 4; ++j) {
            float v = c[i][j];
            s += v;
            if (tcol[tx * 4 + j] == tr) sm += v;
        }
        atomicAdd(&redS[r], s);
        atomicAdd(&redSame[r], sm);
    }
    __syncthreads();
    if (tid < BM) {
        atomicAdd(&S[i0 + tid],    redS[tid]);
        atomicAdd(&SAME[i0 + tid], redSame[tid]);
    }
}

__global__ __launch_bounds__(128) void loss_kernel(
        const float* __restrict__ X, const int* __restrict__ T,
        const float* __restrict__ K, const float* __restrict__ colinv,
        double* __restrict__ acc) {
    const int row = blockIdx.x;
    const int tid = threadIdx.x;
    __shared__ float xs[EMB];
    *(float4*)&xs[tid * 4] = *(const float4*)&X[(size_t)row * EMB + tid * 4];
    __syncthreads();

    const int tgt = T[row];
    const int c = tid;
    float logit = -1e30f;
    if (c < NCLS) {
        float d = 0.f;
        #pragma unroll 4
        for (int k = 0; k < EMB; ++k) d = fmaf(K[k * NCLS + c], xs[k], d);
        float cosv = d * colinv[c];
        cosv = fminf(1.f, fmaxf(-1.f, cosv));
        logit = (cosv - (c == tgt ? BETA_F : 0.f)) * ALPHA_F;
    }

    __shared__ float rv[128];
    __shared__ int   ri[128];
    __shared__ float Lt;
    if (c == tgt) Lt = logit;

    rv[tid] = logit;
    __syncthreads();
    #pragma unroll
    for (int s = 64; s > 0; s >>= 1) {
        if (tid < s) rv[tid] = fmaxf(rv[tid], rv[tid + s]);
        __syncthreads();
    }
    const float m = rv[0];
    __syncthreads();

    rv[tid] = (c < NCLS) ? expf(logit - m) : 0.f;
    __syncthreads();
    #pragma unroll
    for (int s = 64; s > 0; s >>= 1) {
        if (tid < s) rv[tid] += rv[tid + s];
        __syncthreads();
    }
    const float lse = m + logf(rv[0]);
    __syncthreads();

    rv[tid] = logit;
    ri[tid] = (c < NCLS) ? c : 0x7fffffff;
    __syncthreads();
    #pragma unroll
    for (int s = 64; s > 0; s >>= 1) {
        if (tid < s) {
            float vo = rv[tid + s]; int io = ri[tid + s];
            if (vo > rv[tid] || (vo == rv[tid] && io < ri[tid])) { rv[tid] = vo; ri[tid] = io; }
        }
        __syncthreads();
    }

    if (tid == 0) {
        float loss_i = lse - Lt;
        atomicAdd(&acc[0], (double)loss_i);
        atomicAdd(&acc[1], (ri[0] == tgt) ? 1.0 : 0.0);
    }
}

__global__ void finalize_kernel(
        const float* __restrict__ X, const int* __restrict__ T,
        const int* __restrict__ hist, const float* __restrict__ S,
        const float* __restrict__ SAME, double* __restrict__ acc) {
    int r = blockIdx.x * blockDim.x + threadIdx.x;
    if (r >= NROWS) return;
    const float* x = X + (size_t)r * EMB;
    double d = 0.0;
    for (int k = 0; k < EMB; ++k) d = fma((double)x[k], (double)x[k], d);
    int h = hist[T[r]];
    float same = SAME[r];
    float pos_sum; int pos_cnt;
    if (d < 1.0) { pos_sum = same;            pos_cnt = h;     }
    else         { pos_sum = same - (float)d; pos_cnt = h - 1; }
    float neg_sum = S[r] - same;
    int   neg_cnt = NROWS - h;
    atomicAdd(&acc[2], (double)(pos_sum / (float)pos_cnt));
    atomicAdd(&acc[3], (double)(neg_sum / (float)neg_cnt));
}

__global__ void out_kernel(const double* __restrict__ acc, float* __restrict__ out) {
    if (threadIdx.x == 0) {
        out[0] = (float)(acc[0] / NROWS);
        out[1] = (float)(acc[1] / NROWS);
        out[2] = (float)(acc[2] / NROWS);
        out[3] = (float)(acc[3] / NROWS);
    }
}

extern "C" void kernel_launch(void* const* d_in, const int* in_sizes, int n_in,
                              void* d_out, int out_size, void* d_ws, size_t ws_size,
                              hipStream_t stream) {
    const float* X = (const float*)d_in[0];   // [8192, 512]
    const int*   T = (const int*)d_in[1];     // [8192]
    const float* K = (const float*)d_in[2];   // [512, 98]
    float* out = (float*)d_out;               // 4 scalars

    const size_t KBT_BYTES    = (size_t)NCPAD * EMB * sizeof(unsigned short); // 128 KB
    const size_t V_BYTES      = (size_t)NCLS * EMB * sizeof(float);           // 200704 B
    const size_t BUCKET_BYTES = (size_t)NCLS * MAXPER * sizeof(int);          // 100352 B
    const size_t ZONE_BYTES   = 4 * 8 + 128 * 8 + 128 * 4 + 512 * 4;          // 3616 B

    if (ws_size >= KBT_BYTES + V_BYTES + BUCKET_BYTES + ZONE_BYTES + 256) {
        unsigned short* KbT = (unsigned short*)d_ws;
        float* V      = (float*)((char*)d_ws + KBT_BYTES);
        int*   bucket = (int*)((char*)d_ws + KBT_BYTES + V_BYTES);
        char*  zz     = (char*)d_ws + KBT_BYTES + V_BYTES + BUCKET_BYTES;
        double* acc    = (double*)zz;
        double* posneg = acc + 4;
        int*    cnt    = (int*)(posneg + 128);
        float*  usum   = (float*)(cnt + 128);

        init_scatter_kernel<<<1, 1024, 0, stream>>>(T, cnt, bucket, acc, posneg, usum);
        classv_kernel<<<816, 256, 0, stream>>>(X, K, cnt, bucket, V, usum, KbT);
        main_kernel<<<NROWS / 16, 512, 0, stream>>>(X, KbT, T, cnt, V, usum, acc, posneg);
        out2_kernel<<<1, 64, 0, stream>>>(acc, posneg, out);
    } else {
        // fallback: f32 path (small workspace)
        const size_t FB_BYTES = sizeof(double) * 4 + sizeof(int) * NCLS
                              + sizeof(float) * (NCLS + 2 * NROWS);
        double* acc    = (double*)d_ws;
        int*    hist   = (int*)(acc + 4);
        float*  colinv = (float*)(hist + NCLS);
        float*  S      = colinv + NCLS;
        float*  SAME   = S + NROWS;

        hipMemsetAsync(d_ws, 0, FB_BYTES, stream);
        hist_kernel<<<(NROWS + 255) / 256, 256, 0, stream>>>(T, hist);
        colnorm_kernel<<<NCLS, 64, 0, stream>>>(K, colinv);
        simred_kernel<<<dim3(NROWS / BM, NROWS / BN), 256, 0, stream>>>(X, T, S, SAME);
        loss_kernel<<<NROWS, 128, 0, stream>>>(X, T, K, colinv, acc);
        finalize_kernel<<<(NROWS + 255) / 256, 256, 0, stream>>>(X, T, hist, S, SAME, acc);
        out_kernel<<<1, 64, 0, stream>>>(acc, out);
    }
}